// Round 2
// baseline (384.121 us; speedup 1.0000x reference)
//
#include <hip/hip_runtime.h>

// ---------------------------------------------------------------------------
// LlamaDifferentialAttentionBase on MI355X (gfx950)
// B=1, S=2048, HID=2048, H=32, D=64. All inputs fp32; output fp32.
// R8: diff_attn TLP push — waves split along KV (ks-halves) instead of Q,
//     halving per-wave ka/vb register pressure -> 3 blocks/CU (was 2).
//     O/csum ks-partials merged once via LDS at end. Grid 512->1024 blocks
//     of 64 q-rows. qkv/gemm_bt raised to 4 blocks/CU (regs fit exactly).
//     cvt_all: 8 floats/thread, 16B stores.
// ---------------------------------------------------------------------------

typedef __bf16 bf16;
typedef __bf16 bf16x4 __attribute__((ext_vector_type(4)));
typedef __bf16 bf16x8 __attribute__((ext_vector_type(8)));
typedef float  f32x4  __attribute__((ext_vector_type(4)));
typedef unsigned int u32;
typedef u32 u32x2 __attribute__((ext_vector_type(2)));
typedef u32 u32x4 __attribute__((ext_vector_type(4)));

#define MFMA(a, b, c) __builtin_amdgcn_mfma_f32_16x16x32_bf16((a), (b), (c), 0, 0, 0)

#define S_LEN   2048
#define HID_DIM 2048
#define NHEAD   32
#define HD      64
#define QKV_N   10240                 // 4096 (q) + 4096 (k) + 2048 (v)
#define LAM_INIT 0.7836057665316245f  // 0.8 - 0.6*exp(-0.3*12)
#define ONE_MINUS_LAM_INIT 0.21639423346837553f
#define QSCALE  0.18033688011112042f  // (1/sqrt(64)) * log2(e)
#define RMS_EPS 1e-6f
#define L2T     0.4152410118609203f   // log2(10000)/32

// async global->LDS, 16B per lane; LDS dest = wave-uniform base + lane*16
__device__ __forceinline__ void gld16(const void* g, void* l) {
    __builtin_amdgcn_global_load_lds(
        (const __attribute__((address_space(1))) void*)g,
        (__attribute__((address_space(3))) void*)l, 16, 0, 0);
}

// Build PV A-operand dwords from QK^T accumulator dwords (validated in R7).
// x = packed P[k base..+3][q] of k-block (2ks), y = same of k-block (2ks+1),
// producer quad (k%16)/4 -> consumer quad (k%32)/8:
//   wlo = {x.g0, x.g2, y.g0, y.g2},  whi = {x.g1, x.g3, y.g1, y.g3}.
__device__ __forceinline__ void pa_build(u32 x, u32 y, int quad, u32& wlo, u32& whi) {
#if __has_builtin(__builtin_amdgcn_permlane32_swap) && __has_builtin(__builtin_amdgcn_permlane16_swap)
    u32x2 s = __builtin_amdgcn_permlane32_swap(x, y, false, false);
    u32x2 t = __builtin_amdgcn_permlane16_swap(s.x, s.y, false, false);
    wlo = t.x;
    whi = t.y;
#else
    const u32 x16 = (u32)__shfl_xor((int)x, 16, 64);
    const u32 x32 = (u32)__shfl_xor((int)x, 32, 64);
    const u32 x48 = (u32)__shfl_xor((int)x, 48, 64);
    const u32 y16 = (u32)__shfl_xor((int)y, 16, 64);
    const u32 y32 = (u32)__shfl_xor((int)y, 32, 64);
    const u32 y48 = (u32)__shfl_xor((int)y, 48, 64);
    wlo = (quad == 0) ? x   : (quad == 1) ? x48 : (quad == 2) ? y32 : y16;
    whi = (quad == 0) ? x16 : (quad == 1) ? x32 : (quad == 2) ? y48 : y;
#endif
}

// ---------------------------------------------------------------------------
// Fused fp32->bf16 for all 5 tensors + lambda scalar (last block).
// 8 floats/thread, 16B bf16x8 stores.
// ---------------------------------------------------------------------------
__global__ void cvt_all(const float* __restrict__ hs, const float* __restrict__ Wq,
                        const float* __restrict__ Wk, const float* __restrict__ Wv,
                        const float* __restrict__ Wo,
                        const float* __restrict__ lq1, const float* __restrict__ lk1,
                        const float* __restrict__ lq2, const float* __restrict__ lk2,
                        bf16* __restrict__ hsb, bf16* __restrict__ Wb,
                        bf16* __restrict__ Wob, float* __restrict__ lam_out) {
    const int bid = blockIdx.x;
    if (bid >= 14336) {               // lambda block
        const int t = threadIdx.x;
        if (t < 64) {
            float a = lq1[t] * lk1[t];
            float b = lq2[t] * lk2[t];
            #pragma unroll
            for (int off = 32; off > 0; off >>= 1) {
                a += __shfl_xor(a, off, 64);
                b += __shfl_xor(b, off, 64);
            }
            if (t == 0) lam_out[0] = expf(a) - expf(b) + LAM_INIT;
        }
        return;
    }
    const float* src; bf16* dst; int off;
    if      (bid <  2048) { src = hs; dst = hsb;            off = bid;         }
    else if (bid <  6144) { src = Wq; dst = Wb;             off = bid - 2048;  }
    else if (bid < 10240) { src = Wk; dst = Wb +  8388608;  off = bid - 6144;  }
    else if (bid < 12288) { src = Wv; dst = Wb + 16777216;  off = bid - 10240; }
    else                  { src = Wo; dst = Wob;            off = bid - 12288; }
    const int i = off * 2048 + threadIdx.x * 8;
    float4 a = *(const float4*)(src + i);
    float4 b = *(const float4*)(src + i + 4);
    bf16x8 o = { (bf16)a.x, (bf16)a.y, (bf16)a.z, (bf16)a.w,
                 (bf16)b.x, (bf16)b.y, (bf16)b.z, (bf16)b.w };
    *(bf16x8*)(dst + i) = o;
}

// ---------------------------------------------------------------------------
// Fused QKV GEMM + RoPE + head split + V transpose. (structure = R6;
// occupancy 3->4 blocks/CU: current alloc is exactly 64 VGPR + 64 AGPR = 128)
// ---------------------------------------------------------------------------
__global__ __launch_bounds__(256, 4)
void qkv_rope_gemm(const bf16* __restrict__ A, const bf16* __restrict__ B,
                   bf16* __restrict__ Q1, bf16* __restrict__ Q2,
                   bf16* __restrict__ K1, bf16* __restrict__ K2,
                   bf16* __restrict__ Vt) {
    __shared__ __align__(16) bf16 As[128 * 64];
    __shared__ __align__(16) bf16 Bs[128 * 64];
    const int tid  = threadIdx.x;
    const int wave = tid >> 6, lane = tid & 63;
    const int wm = wave >> 1, wn = wave & 1;      // wm: s-half, wn: d-half
    const int l = lane & 15, quad = lane >> 4;
    const int m0 = blockIdx.y * 128, n0 = blockIdx.x * 128;

    f32x4 acc[4][4];                              // [wi (d)][hi (s)]
    #pragma unroll
    for (int i = 0; i < 4; ++i)
        #pragma unroll
        for (int j = 0; j < 4; ++j) acc[i][j] = (f32x4){0.f, 0.f, 0.f, 0.f};

    const int rr  = tid >> 3;
    const int csw = ((tid & 7) ^ (rr & 7)) * 8;
    const bf16* Ag = A + (size_t)(m0 + rr) * HID_DIM + csw;
    const bf16* Bg = B + (size_t)(n0 + rr) * HID_DIM + csw;

    for (int kt = 0; kt < HID_DIM; kt += 64) {
        __syncthreads();
        #pragma unroll
        for (int j = 0; j < 4; ++j) {
            gld16(Ag + (size_t)(32 * j) * HID_DIM + kt, As + j * 2048 + tid * 8);
            gld16(Bg + (size_t)(32 * j) * HID_DIM + kt, Bs + j * 2048 + tid * 8);
        }
        __syncthreads();

        #pragma unroll
        for (int ks = 0; ks < 2; ++ks) {
            const int co = (((ks << 2) | quad) ^ (l & 7)) << 3;
            bf16x8 hf[4], wf[4];
            #pragma unroll
            for (int hi = 0; hi < 4; ++hi)
                hf[hi] = *(const bf16x8*)(As + (wm * 64 + hi * 16 + l) * 64 + co);
            #pragma unroll
            for (int wi = 0; wi < 4; ++wi)
                wf[wi] = *(const bf16x8*)(Bs + (wn * 64 + wi * 16 + l) * 64 + co);
            #pragma unroll
            for (int wi = 0; wi < 4; ++wi)
                #pragma unroll
                for (int hi = 0; hi < 4; ++hi)
                    acc[wi][hi] = MFMA(wf[wi], hf[hi], acc[wi][hi]);  // row=d, col=s
        }
    }

    // ---- epilogue: RoPE + store ----
    const int c = n0 + wn * 64;                   // global qkv column base
    const int sbase = m0 + wm * 64;
    bf16* dst; int off; float scale = 1.0f; bool isv = false;
    if      (c < 2048) { dst = Q1; off = c;        scale = QSCALE; }
    else if (c < 4096) { dst = Q2; off = c - 2048; scale = QSCALE; }
    else if (c < 6144) { dst = K1; off = c - 4096; }
    else if (c < 8192) { dst = K2; off = c - 6144; }
    else               { isv = true; off = c - 8192; }
    const int h = off >> 6;                       // off is 64-aligned

    if (!isv) {
        float invf[2][4];
        #pragma unroll
        for (int p = 0; p < 2; ++p)
            #pragma unroll
            for (int r = 0; r < 4; ++r)
                invf[p][r] = exp2f(-(float)(p * 16 + quad * 4 + r) * L2T);

        #pragma unroll
        for (int hi = 0; hi < 4; ++hi) {
            const float s = (float)(sbase + hi * 16 + l);
            float cs[2][4], sn[2][4];
            #pragma unroll
            for (int p = 0; p < 2; ++p)
                #pragma unroll
                for (int r = 0; r < 4; ++r) {
                    const float ang = s * invf[p][r];
                    cs[p][r] = __cosf(ang);
                    sn[p][r] = __sinf(ang);
                }
            bf16* rowp = dst + ((size_t)h * S_LEN + sbase + hi * 16 + l) * HD + quad * 4;
            #pragma unroll
            for (int wi = 0; wi < 4; ++wi) {
                const int p = wi & 1;
                const float sign = (wi < 2) ? -1.0f : 1.0f;
                bf16x4 o;
                #pragma unroll
                for (int r = 0; r < 4; ++r)
                    o[r] = (bf16)((acc[wi][hi][r] * cs[p][r] +
                                   sign * acc[wi ^ 2][hi][r] * sn[p][r]) * scale);
                *(bf16x4*)(rowp + wi * 16) = o;
            }
        }
    } else {
        #pragma unroll
        for (int wi = 0; wi < 4; ++wi)
            #pragma unroll
            for (int r = 0; r < 4; ++r) {
                bf16* vrow = Vt + ((size_t)h * HD + wi * 16 + quad * 4 + r) * S_LEN + sbase;
                #pragma unroll
                for (int hi = 0; hi < 4; ++hi)
                    vrow[hi * 16 + l] = (bf16)acc[wi][hi][r];
            }
    }
}

// ---------------------------------------------------------------------------
// GEMM: C[M,N] = A[M,K] * B[N,K]^T, split-K partials (O-proj). 4 blocks/CU.
// ---------------------------------------------------------------------------
__global__ __launch_bounds__(256, 4)
void gemm_bt_splitk(const bf16* __restrict__ A, const bf16* __restrict__ B,
                    float* __restrict__ Cout, int M, int N, int K_total, int K_part) {
    __shared__ __align__(16) bf16 As[128 * 64];
    __shared__ __align__(16) bf16 Bs[128 * 64];
    const int tid  = threadIdx.x;
    const int wave = tid >> 6, lane = tid & 63;
    const int wm = wave >> 1, wn = wave & 1;
    const int l = lane & 15, quad = lane >> 4;
    const int m0 = blockIdx.y * 128, n0 = blockIdx.x * 128;
    const int kz = blockIdx.z * K_part;

    f32x4 acc[4][4];
    #pragma unroll
    for (int i = 0; i < 4; ++i)
        #pragma unroll
        for (int j = 0; j < 4; ++j) acc[i][j] = (f32x4){0.f, 0.f, 0.f, 0.f};

    const int rr  = tid >> 3;
    const int csw = ((tid & 7) ^ (rr & 7)) * 8;
    const bf16* Ag = A + (size_t)(m0 + rr) * K_total + kz + csw;
    const bf16* Bg = B + (size_t)(n0 + rr) * K_total + kz + csw;

    for (int kt = 0; kt < K_part; kt += 64) {
        __syncthreads();
        #pragma unroll
        for (int j = 0; j < 4; ++j) {
            gld16(Ag + (size_t)(32 * j) * K_total + kt, As + j * 2048 + tid * 8);
            gld16(Bg + (size_t)(32 * j) * K_total + kt, Bs + j * 2048 + tid * 8);
        }
        __syncthreads();

        #pragma unroll
        for (int ks = 0; ks < 2; ++ks) {
            const int co = (((ks << 2) | quad) ^ (l & 7)) << 3;
            bf16x8 af[4], bfr[4];
            #pragma unroll
            for (int mi = 0; mi < 4; ++mi)
                af[mi] = *(const bf16x8*)(As + (wm * 64 + mi * 16 + l) * 64 + co);
            #pragma unroll
            for (int ni = 0; ni < 4; ++ni)
                bfr[ni] = *(const bf16x8*)(Bs + (wn * 64 + ni * 16 + l) * 64 + co);
            #pragma unroll
            for (int mi = 0; mi < 4; ++mi)
                #pragma unroll
                for (int ni = 0; ni < 4; ++ni)
                    acc[mi][ni] = MFMA(af[mi], bfr[ni], acc[mi][ni]);
        }
    }

    float* Pf = Cout + (size_t)blockIdx.z * M * N;
    #pragma unroll
    for (int mi = 0; mi < 4; ++mi)
        #pragma unroll
        for (int ni = 0; ni < 4; ++ni)
            #pragma unroll
            for (int r = 0; r < 4; ++r) {
                const int row = m0 + wm * 64 + mi * 16 + quad * 4 + r;
                const int col = n0 + wn * 64 + ni * 16 + l;
                Pf[(size_t)row * N + col] = acc[mi][ni][r];
            }
}

// split-K reduce: out[i] = p[i] + p[n+i]  (fp32, float4)
__global__ void reduce_add(const float* __restrict__ p, float* __restrict__ out, int n) {
    const int i = (blockIdx.x * 256 + threadIdx.x) * 4;
    float4 a = *(const float4*)(p + i);
    float4 b = *(const float4*)(p + n + i);
    float4 o = { a.x + b.x, a.y + b.y, a.z + b.z, a.w + b.w };
    *(float4*)(out + i) = o;
}

// ---------------------------------------------------------------------------
// Differential flash attention, R8: KV-split waves for 3 blocks/CU.
//  Block = (head h, 64 q-rows). 4 waves = sid(2: softmax variant) x
//  ks(2: kv-half of each 64-row tile). Per wave-tile: 16 QK MFMA (2 mk-rows
//  x 4 g x 2 d-halves) + 16 PV MFMA (its ks only). ka[2][2]+vb[4] = 32 VGPR
//  (was 64) -> fits 3 waves/EU. O/csum are ks-partials, merged once via LDS
//  after the loop. Total MFMA/LDS-read/exp counts identical to R7.
//  Double-buffered staging + issue-early/drain-late prefetch kept from R7.
// ---------------------------------------------------------------------------
__global__ __launch_bounds__(256, 3)
void diff_attn(const bf16* __restrict__ Q1, const bf16* __restrict__ K1,
               const bf16* __restrict__ Q2, const bf16* __restrict__ K2,
               const bf16* __restrict__ Vt, const float* __restrict__ lam_p,
               const float* __restrict__ subln_w, bf16* __restrict__ attn_out) {
    const int bid   = blockIdx.x;
    const int h     = (bid >> 1) & 31;
    const int qpair = bid >> 6;                       // 0..15
    const int qb    = (bid & 1) ? qpair : (31 - qpair);  // 0..31, long+short paired
    const int q0    = qb * 64;
    const int tid  = threadIdx.x;
    const int wave = tid >> 6, lane = tid & 63;
    const int sid  = wave >> 1, ks = wave & 1;        // variant, kv-half
    const int l    = lane & 15, quad = lane >> 4;

    // 2 x 24576 B double buffer: per buffer {K1 8K | K2 8K | Vt 8K}.
    // Epilogue reuse: dumpO sid0 @0 (17408), sid1 @17408; dumpC @34816+sid*1024;
    // epi fp32 [64][65] @0 after merge barrier.
    __shared__ __align__(16) char smem[49152];

    const bf16* Qh  = (sid ? Q2 : Q1) + ((size_t)h * S_LEN + q0) * HD;
    const bf16* K1g = K1 + (size_t)h * S_LEN * HD;
    const bf16* K2g = K2 + (size_t)h * S_LEN * HD;
    const bf16* Vtg = Vt + (size_t)h * HD * S_LEN;

    const int rr  = tid >> 3;
    const int csw = ((tid & 7) ^ (rr & 7)) * 8;
    const int sw8 = l & 7;

    auto stage = [&](int kv, int bufb) {
        const bf16* k1p = K1g + (size_t)(kv + rr) * HD + csw;
        const bf16* k2p = K2g + (size_t)(kv + rr) * HD + csw;
        const bf16* vtp = Vtg + (size_t)rr * S_LEN + kv + csw;
        bf16* d1 = (bf16*)(smem + bufb)         + tid * 8;
        bf16* d2 = (bf16*)(smem + bufb + 8192)  + tid * 8;
        bf16* dv = (bf16*)(smem + bufb + 16384) + tid * 8;
        gld16(k1p,                       d1);
        gld16(k1p + (size_t)32 * HD,     d1 + 2048);
        gld16(k2p,                       d2);
        gld16(k2p + (size_t)32 * HD,     d2 + 2048);
        gld16(vtp,                       dv);
        gld16(vtp + (size_t)32 * S_LEN,  dv + 2048);
    };

    bf16x8 qf[4][2];
    #pragma unroll
    for (int g = 0; g < 4; ++g)
        #pragma unroll
        for (int dh = 0; dh < 2; ++dh)
            qf[g][dh] = *(const bf16x8*)(Qh + (g * 16 + l) * HD + dh * 32 + quad * 8);

    f32x4 O[4][4];                                 // [g (q)][nd (d)] ks-partial
    #pragma unroll
    for (int g = 0; g < 4; ++g)
        #pragma unroll
        for (int nd = 0; nd < 4; ++nd)
            O[g][nd] = (f32x4){0.f, 0.f, 0.f, 0.f};
    float csum[4] = {0.f, 0.f, 0.f, 0.f};          // ks-partial row sums

    const int T = qb + 1;

    stage(0, 0);
    asm volatile("s_waitcnt vmcnt(0)" ::: "memory");
    __builtin_amdgcn_s_barrier();

    for (int t = 0; t < T; ++t) {
        const int bb = (t & 1) * 24576;
        if (t + 1 < T) stage((t + 1) * 64, 24576 - bb);

        {
            const bool diag = (t == qb);
            const bf16* Ksm = (const bf16*)(smem + bb + (sid ? 8192 : 0));
            const bf16* Vts = (const bf16*)(smem + bb + 16384);

            // K-frags: only this wave's kv-half (global mk = 2*ks + mk)
            bf16x8 ka[2][2];
            #pragma unroll
            for (int mk = 0; mk < 2; ++mk) {
                const int krow = ((2 * ks + mk) * 16 + l) * 64;
                ka[mk][0] = *(const bf16x8*)(Ksm + krow + ((quad ^ sw8) << 3));
                ka[mk][1] = *(const bf16x8*)(Ksm + krow + (((4 + quad) ^ sw8) << 3));
            }
            // V-frags: only this wave's ks slot group
            bf16x8 vb[4];
            #pragma unroll
            for (int nd = 0; nd < 4; ++nd)
                vb[nd] = *(const bf16x8*)(Vts + (nd * 16 + l) * 64 +
                                          ((((ks << 2) + quad) ^ sw8) << 3));

            __builtin_amdgcn_s_setprio(1);
            #pragma unroll
            for (int g = 0; g < 4; ++g) {
                f32x4 c[2];
                #pragma unroll
                for (int mk = 0; mk < 2; ++mk) {
                    c[mk] = (f32x4){0.f, 0.f, 0.f, 0.f};
                    c[mk] = MFMA(ka[mk][0], qf[g][0], c[mk]);
                    c[mk] = MFMA(ka[mk][1], qf[g][1], c[mk]);
                }
                u32 dw[2][2];
                float lsum = 0.f;
                #pragma unroll
                for (int mk = 0; mk < 2; ++mk) {
                    float p[4];
                    #pragma unroll
                    for (int r = 0; r < 4; ++r) {
                        p[r] = __builtin_amdgcn_exp2f(c[mk][r]);
                        if (diag && ((2 * ks + mk) * 16 + quad * 4 + r > g * 16 + l))
                            p[r] = 0.f;
                        lsum += p[r];
                    }
                    asm("v_cvt_pk_bf16_f32 %0, %1, %2" : "=v"(dw[mk][0]) : "v"(p[0]), "v"(p[1]));
                    asm("v_cvt_pk_bf16_f32 %0, %1, %2" : "=v"(dw[mk][1]) : "v"(p[2]), "v"(p[3]));
                }
                csum[g] += lsum;

                u32 w0, w1, w2, w3;
                pa_build(dw[0][0], dw[1][0], quad, w0, w2);
                pa_build(dw[0][1], dw[1][1], quad, w1, w3);
                u32x4 wv = {w0, w1, w2, w3};
                bf16x8 pa;
                __builtin_memcpy(&pa, &wv, 16);

                #pragma unroll
                for (int nd = 0; nd < 4; ++nd)
                    O[g][nd] = MFMA(pa, vb[nd], O[g][nd]);
            }
            __builtin_amdgcn_s_setprio(0);
        }

        asm volatile("s_waitcnt vmcnt(0)" ::: "memory");
        __builtin_amdgcn_s_barrier();
    }

    // ---------------- merge ks-halves ----------------
    __syncthreads();
    float* dO = (float*)(smem + sid * 17408);      // [lane][68] fp32, 16B-aligned
    float* dC = (float*)(smem + 34816 + sid * 1024);
    if (ks == 1) {
        #pragma unroll
        for (int g = 0; g < 4; ++g)
            #pragma unroll
            for (int nd = 0; nd < 4; ++nd)
                *(f32x4*)(dO + lane * 68 + (g * 4 + nd) * 4) = O[g][nd];
        #pragma unroll
        for (int g = 0; g < 4; ++g) dC[g * 64 + lane] = csum[g];
    }
    __syncthreads();
    if (ks == 0) {
        #pragma unroll
        for (int g = 0; g < 4; ++g) {
            #pragma unroll
            for (int nd = 0; nd < 4; ++nd) {
                f32x4 o = *(const f32x4*)(dO + lane * 68 + (g * 4 + nd) * 4);
                O[g][nd] += o;
            }
            csum[g] += dC[g * 64 + lane];
        }
    }

    // full row-sums: reduce across quads (lanes same l, different quad)
    #pragma unroll
    for (int g = 0; g < 4; ++g) {
        csum[g] += __shfl_xor(csum[g], 16, 64);
        csum[g] += __shfl_xor(csum[g], 32, 64);
    }
    __syncthreads();

    // ---------------- epilogue (ks==0 waves only) ----------------
    float* epi = (float*)smem;                     // [64][65] fp32

    if (sid == 1 && ks == 0) {
        const float lam = lam_p[0];
        #pragma unroll
        for (int mi = 0; mi < 4; ++mi)
            #pragma unroll
            for (int r = 0; r < 4; ++r) {
                const float inv = lam / __shfl(csum[mi], quad * 4 + r, 64);
                const int row = mi * 16 + quad * 4 + r;
                #pragma unroll
                for (int ni = 0; ni < 4; ++ni)
                    epi[row * 65 + ni * 16 + l] = O[mi][ni][r] * inv;
            }
    }
    __syncthreads();

    if (sid == 0 && ks == 0) {
        float sw[4];
        #pragma unroll
        for (int ni = 0; ni < 4; ++ni) sw[ni] = subln_w[ni * 16 + l];

        #pragma unroll
        for (int mi = 0; mi < 4; ++mi) {
            float inv1[4];
            #pragma unroll
            for (int r = 0; r < 4; ++r)
                inv1[r] = 1.0f / __shfl(csum[mi], quad * 4 + r, 64);

            float v[4][4]; float ssq[4] = {0.f, 0.f, 0.f, 0.f};
            #pragma unroll
            for (int ni = 0; ni < 4; ++ni)
                #pragma unroll
                for (int r = 0; r < 4; ++r) {
                    const int row = mi * 16 + quad * 4 + r;
                    const float x = O[mi][ni][r] * inv1[r] - epi[row * 65 + ni * 16 + l];
                    v[ni][r] = x;
                    ssq[r] += x * x;
                }
            #pragma unroll
            for (int r = 0; r < 4; ++r) {
                float s = ssq[r];
                s += __shfl_xor(s, 1, 64);
                s += __shfl_xor(s, 2, 64);
                s += __shfl_xor(s, 4, 64);
                s += __shfl_xor(s, 8, 64);
                ssq[r] = rsqrtf(s * (1.0f / 64.0f) + RMS_EPS) * ONE_MINUS_LAM_INIT;
            }
            #pragma unroll
            for (int ni = 0; ni < 4; ++ni)
                #pragma unroll
                for (int r = 0; r < 4; ++r) {
                    const int row = q0 + mi * 16 + quad * 4 + r;
                    attn_out[(size_t)row * HID_DIM + h * 64 + ni * 16 + l] =
                        (bf16)(v[ni][r] * ssq[r] * sw[ni]);
                }
        }
    }
}

// ---------------------------------------------------------------------------
// Workspace layout (bytes):
//   hsb   @ 0           8,388,608   hidden bf16
//   Wb    @ 8388608    41,943,040   Wq|Wk|Wv bf16
//   Wob   @ 50331648    8,388,608   Wo bf16
//   part  @ 58720256   33,554,432   O-proj split-K fp32 partials (2x)
//   Q1    @ 100663296   8,388,608
//   K1    @ 109051904   8,388,608
//   Q2    @ 117440512   8,388,608
//   K2    @ 125829120   8,388,608
//   Vt    @ 134217728   8,388,608
//   abuf  @ 142606336   8,388,608
//   lam   @ 150994944   4
// ---------------------------------------------------------------------------
extern "C" void kernel_launch(void* const* d_in, const int* in_sizes, int n_in,
                              void* d_out, int out_size, void* d_ws, size_t ws_size,
                              hipStream_t stream) {
    const float* hs  = (const float*)d_in[0];
    const float* Wq  = (const float*)d_in[1];
    const float* Wk  = (const float*)d_in[2];
    const float* Wv  = (const float*)d_in[3];
    const float* Wo  = (const float*)d_in[4];
    const float* lq1 = (const float*)d_in[5];
    const float* lk1 = (const float*)d_in[6];
    const float* lq2 = (const float*)d_in[7];
    const float* lk2 = (const float*)d_in[8];
    const float* slw = (const float*)d_in[9];

    if (ws_size < 151000000u) return;

    char* ws = (char*)d_ws;
    bf16*  hsb  = (bf16*)(ws);
    bf16*  Wb   = (bf16*)(ws + 8388608);
    bf16*  Wob  = (bf16*)(ws + 50331648);
    float* part = (float*)(ws + 58720256);
    bf16*  Q1b  = (bf16*)(ws + 100663296);
    bf16*  K1b  = (bf16*)(ws + 109051904);
    bf16*  Q2b  = (bf16*)(ws + 117440512);
    bf16*  K2b  = (bf16*)(ws + 125829120);
    bf16*  Vtb  = (bf16*)(ws + 134217728);
    bf16*  abuf = (bf16*)(ws + 142606336);
    float* lamp = (float*)(ws + 150994944);

    // 1) conversions + lambda
    cvt_all<<<14337, 256, 0, stream>>>(hs, Wq, Wk, Wv, Wo, lq1, lk1, lq2, lk2,
                                       hsb, Wb, Wob, lamp);

    // 2) fused QKV projection + RoPE + split + V transpose
    qkv_rope_gemm<<<dim3(QKV_N / 128, S_LEN / 128), 256, 0, stream>>>(
        hsb, Wb, Q1b, Q2b, K1b, K2b, Vtb);

    // 3) differential attention (1024 blocks of 64 q-rows)
    diff_attn<<<1024, 256, 0, stream>>>(Q1b, K1b, Q2b, K2b, Vtb, lamp, slw, abuf);

    // 4) output projection, split-K=2 -> fp32 partials -> reduce to d_out
    gemm_bt_splitk<<<dim3(HID_DIM / 128, S_LEN / 128, 2), 256, 0, stream>>>(
        abuf, Wob, part, S_LEN, HID_DIM, HID_DIM, HID_DIM / 2);
    reduce_add<<<4096, 256, 0, stream>>>(part, (float*)d_out, S_LEN * HID_DIM);
}

// Round 3
// 358.266 us; speedup vs baseline: 1.0722x; 1.0722x over previous
//
#include <hip/hip_runtime.h>

// ---------------------------------------------------------------------------
// LlamaDifferentialAttentionBase on MI355X (gfx950)
// B=1, S=2048, HID=2048, H=32, D=64. All inputs fp32; output fp32.
// R9: diff_attn made PERSISTENT + cost-balanced. Grid = 768 (exactly 3
//     blocks/CU resident; LDS 48K x 3 = 144K, VGPR 84 < 170). Blocks
//     0..511 each own one long item (qb 16..31); blocks 512..767 own two
//     short items (p, 15-p) summing to 17 tiles. Fixes the R8 finding:
//     14.8% occupancy / 60% dead time from a 4-blocks-per-CU imbalanced
//     grid. Wave layout (sid x ks KV-split, in-register P via permlane)
//     kept from R8. qkv/gemm_bt reverted to launch_bounds(256,3).
// ---------------------------------------------------------------------------

typedef __bf16 bf16;
typedef __bf16 bf16x4 __attribute__((ext_vector_type(4)));
typedef __bf16 bf16x8 __attribute__((ext_vector_type(8)));
typedef float  f32x4  __attribute__((ext_vector_type(4)));
typedef unsigned int u32;
typedef u32 u32x2 __attribute__((ext_vector_type(2)));
typedef u32 u32x4 __attribute__((ext_vector_type(4)));

#define MFMA(a, b, c) __builtin_amdgcn_mfma_f32_16x16x32_bf16((a), (b), (c), 0, 0, 0)

#define S_LEN   2048
#define HID_DIM 2048
#define NHEAD   32
#define HD      64
#define QKV_N   10240                 // 4096 (q) + 4096 (k) + 2048 (v)
#define LAM_INIT 0.7836057665316245f  // 0.8 - 0.6*exp(-0.3*12)
#define ONE_MINUS_LAM_INIT 0.21639423346837553f
#define QSCALE  0.18033688011112042f  // (1/sqrt(64)) * log2(e)
#define RMS_EPS 1e-6f
#define L2T     0.4152410118609203f   // log2(10000)/32

// async global->LDS, 16B per lane; LDS dest = wave-uniform base + lane*16
__device__ __forceinline__ void gld16(const void* g, void* l) {
    __builtin_amdgcn_global_load_lds(
        (const __attribute__((address_space(1))) void*)g,
        (__attribute__((address_space(3))) void*)l, 16, 0, 0);
}

// Build PV A-operand dwords from QK^T accumulator dwords (validated in R7/R8).
__device__ __forceinline__ void pa_build(u32 x, u32 y, int quad, u32& wlo, u32& whi) {
#if __has_builtin(__builtin_amdgcn_permlane32_swap) && __has_builtin(__builtin_amdgcn_permlane16_swap)
    u32x2 s = __builtin_amdgcn_permlane32_swap(x, y, false, false);
    u32x2 t = __builtin_amdgcn_permlane16_swap(s.x, s.y, false, false);
    wlo = t.x;
    whi = t.y;
#else
    const u32 x16 = (u32)__shfl_xor((int)x, 16, 64);
    const u32 x32 = (u32)__shfl_xor((int)x, 32, 64);
    const u32 x48 = (u32)__shfl_xor((int)x, 48, 64);
    const u32 y16 = (u32)__shfl_xor((int)y, 16, 64);
    const u32 y32 = (u32)__shfl_xor((int)y, 32, 64);
    const u32 y48 = (u32)__shfl_xor((int)y, 48, 64);
    wlo = (quad == 0) ? x   : (quad == 1) ? x48 : (quad == 2) ? y32 : y16;
    whi = (quad == 0) ? x16 : (quad == 1) ? x32 : (quad == 2) ? y48 : y;
#endif
}

// ---------------------------------------------------------------------------
// Fused fp32->bf16 for all 5 tensors + lambda scalar (last block).
// ---------------------------------------------------------------------------
__global__ void cvt_all(const float* __restrict__ hs, const float* __restrict__ Wq,
                        const float* __restrict__ Wk, const float* __restrict__ Wv,
                        const float* __restrict__ Wo,
                        const float* __restrict__ lq1, const float* __restrict__ lk1,
                        const float* __restrict__ lq2, const float* __restrict__ lk2,
                        bf16* __restrict__ hsb, bf16* __restrict__ Wb,
                        bf16* __restrict__ Wob, float* __restrict__ lam_out) {
    const int bid = blockIdx.x;
    if (bid >= 14336) {               // lambda block
        const int t = threadIdx.x;
        if (t < 64) {
            float a = lq1[t] * lk1[t];
            float b = lq2[t] * lk2[t];
            #pragma unroll
            for (int off = 32; off > 0; off >>= 1) {
                a += __shfl_xor(a, off, 64);
                b += __shfl_xor(b, off, 64);
            }
            if (t == 0) lam_out[0] = expf(a) - expf(b) + LAM_INIT;
        }
        return;
    }
    const float* src; bf16* dst; int off;
    if      (bid <  2048) { src = hs; dst = hsb;            off = bid;         }
    else if (bid <  6144) { src = Wq; dst = Wb;             off = bid - 2048;  }
    else if (bid < 10240) { src = Wk; dst = Wb +  8388608;  off = bid - 6144;  }
    else if (bid < 12288) { src = Wv; dst = Wb + 16777216;  off = bid - 10240; }
    else                  { src = Wo; dst = Wob;            off = bid - 12288; }
    const int i = off * 2048 + threadIdx.x * 8;
    float4 a = *(const float4*)(src + i);
    float4 b = *(const float4*)(src + i + 4);
    bf16x8 o = { (bf16)a.x, (bf16)a.y, (bf16)a.z, (bf16)a.w,
                 (bf16)b.x, (bf16)b.y, (bf16)b.z, (bf16)b.w };
    *(bf16x8*)(dst + i) = o;
}

// ---------------------------------------------------------------------------
// Fused QKV GEMM + RoPE + head split + V transpose. (R7 config restored)
// ---------------------------------------------------------------------------
__global__ __launch_bounds__(256, 3)
void qkv_rope_gemm(const bf16* __restrict__ A, const bf16* __restrict__ B,
                   bf16* __restrict__ Q1, bf16* __restrict__ Q2,
                   bf16* __restrict__ K1, bf16* __restrict__ K2,
                   bf16* __restrict__ Vt) {
    __shared__ __align__(16) bf16 As[128 * 64];
    __shared__ __align__(16) bf16 Bs[128 * 64];
    const int tid  = threadIdx.x;
    const int wave = tid >> 6, lane = tid & 63;
    const int wm = wave >> 1, wn = wave & 1;      // wm: s-half, wn: d-half
    const int l = lane & 15, quad = lane >> 4;
    const int m0 = blockIdx.y * 128, n0 = blockIdx.x * 128;

    f32x4 acc[4][4];                              // [wi (d)][hi (s)]
    #pragma unroll
    for (int i = 0; i < 4; ++i)
        #pragma unroll
        for (int j = 0; j < 4; ++j) acc[i][j] = (f32x4){0.f, 0.f, 0.f, 0.f};

    const int rr  = tid >> 3;
    const int csw = ((tid & 7) ^ (rr & 7)) * 8;
    const bf16* Ag = A + (size_t)(m0 + rr) * HID_DIM + csw;
    const bf16* Bg = B + (size_t)(n0 + rr) * HID_DIM + csw;

    for (int kt = 0; kt < HID_DIM; kt += 64) {
        __syncthreads();
        #pragma unroll
        for (int j = 0; j < 4; ++j) {
            gld16(Ag + (size_t)(32 * j) * HID_DIM + kt, As + j * 2048 + tid * 8);
            gld16(Bg + (size_t)(32 * j) * HID_DIM + kt, Bs + j * 2048 + tid * 8);
        }
        __syncthreads();

        #pragma unroll
        for (int ks = 0; ks < 2; ++ks) {
            const int co = (((ks << 2) | quad) ^ (l & 7)) << 3;
            bf16x8 hf[4], wf[4];
            #pragma unroll
            for (int hi = 0; hi < 4; ++hi)
                hf[hi] = *(const bf16x8*)(As + (wm * 64 + hi * 16 + l) * 64 + co);
            #pragma unroll
            for (int wi = 0; wi < 4; ++wi)
                wf[wi] = *(const bf16x8*)(Bs + (wn * 64 + wi * 16 + l) * 64 + co);
            #pragma unroll
            for (int wi = 0; wi < 4; ++wi)
                #pragma unroll
                for (int hi = 0; hi < 4; ++hi)
                    acc[wi][hi] = MFMA(wf[wi], hf[hi], acc[wi][hi]);  // row=d, col=s
        }
    }

    // ---- epilogue: RoPE + store ----
    const int c = n0 + wn * 64;                   // global qkv column base
    const int sbase = m0 + wm * 64;
    bf16* dst; int off; float scale = 1.0f; bool isv = false;
    if      (c < 2048) { dst = Q1; off = c;        scale = QSCALE; }
    else if (c < 4096) { dst = Q2; off = c - 2048; scale = QSCALE; }
    else if (c < 6144) { dst = K1; off = c - 4096; }
    else if (c < 8192) { dst = K2; off = c - 6144; }
    else               { isv = true; off = c - 8192; }
    const int h = off >> 6;                       // off is 64-aligned

    if (!isv) {
        float invf[2][4];
        #pragma unroll
        for (int p = 0; p < 2; ++p)
            #pragma unroll
            for (int r = 0; r < 4; ++r)
                invf[p][r] = exp2f(-(float)(p * 16 + quad * 4 + r) * L2T);

        #pragma unroll
        for (int hi = 0; hi < 4; ++hi) {
            const float s = (float)(sbase + hi * 16 + l);
            float cs[2][4], sn[2][4];
            #pragma unroll
            for (int p = 0; p < 2; ++p)
                #pragma unroll
                for (int r = 0; r < 4; ++r) {
                    const float ang = s * invf[p][r];
                    cs[p][r] = __cosf(ang);
                    sn[p][r] = __sinf(ang);
                }
            bf16* rowp = dst + ((size_t)h * S_LEN + sbase + hi * 16 + l) * HD + quad * 4;
            #pragma unroll
            for (int wi = 0; wi < 4; ++wi) {
                const int p = wi & 1;
                const float sign = (wi < 2) ? -1.0f : 1.0f;
                bf16x4 o;
                #pragma unroll
                for (int r = 0; r < 4; ++r)
                    o[r] = (bf16)((acc[wi][hi][r] * cs[p][r] +
                                   sign * acc[wi ^ 2][hi][r] * sn[p][r]) * scale);
                *(bf16x4*)(rowp + wi * 16) = o;
            }
        }
    } else {
        #pragma unroll
        for (int wi = 0; wi < 4; ++wi)
            #pragma unroll
            for (int r = 0; r < 4; ++r) {
                bf16* vrow = Vt + ((size_t)h * HD + wi * 16 + quad * 4 + r) * S_LEN + sbase;
                #pragma unroll
                for (int hi = 0; hi < 4; ++hi)
                    vrow[hi * 16 + l] = (bf16)acc[wi][hi][r];
            }
    }
}

// ---------------------------------------------------------------------------
// GEMM: C[M,N] = A[M,K] * B[N,K]^T, split-K partials (O-proj).
// ---------------------------------------------------------------------------
__global__ __launch_bounds__(256, 3)
void gemm_bt_splitk(const bf16* __restrict__ A, const bf16* __restrict__ B,
                    float* __restrict__ Cout, int M, int N, int K_total, int K_part) {
    __shared__ __align__(16) bf16 As[128 * 64];
    __shared__ __align__(16) bf16 Bs[128 * 64];
    const int tid  = threadIdx.x;
    const int wave = tid >> 6, lane = tid & 63;
    const int wm = wave >> 1, wn = wave & 1;
    const int l = lane & 15, quad = lane >> 4;
    const int m0 = blockIdx.y * 128, n0 = blockIdx.x * 128;
    const int kz = blockIdx.z * K_part;

    f32x4 acc[4][4];
    #pragma unroll
    for (int i = 0; i < 4; ++i)
        #pragma unroll
        for (int j = 0; j < 4; ++j) acc[i][j] = (f32x4){0.f, 0.f, 0.f, 0.f};

    const int rr  = tid >> 3;
    const int csw = ((tid & 7) ^ (rr & 7)) * 8;
    const bf16* Ag = A + (size_t)(m0 + rr) * K_total + kz + csw;
    const bf16* Bg = B + (size_t)(n0 + rr) * K_total + kz + csw;

    for (int kt = 0; kt < K_part; kt += 64) {
        __syncthreads();
        #pragma unroll
        for (int j = 0; j < 4; ++j) {
            gld16(Ag + (size_t)(32 * j) * K_total + kt, As + j * 2048 + tid * 8);
            gld16(Bg + (size_t)(32 * j) * K_total + kt, Bs + j * 2048 + tid * 8);
        }
        __syncthreads();

        #pragma unroll
        for (int ks = 0; ks < 2; ++ks) {
            const int co = (((ks << 2) | quad) ^ (l & 7)) << 3;
            bf16x8 af[4], bfr[4];
            #pragma unroll
            for (int mi = 0; mi < 4; ++mi)
                af[mi] = *(const bf16x8*)(As + (wm * 64 + mi * 16 + l) * 64 + co);
            #pragma unroll
            for (int ni = 0; ni < 4; ++ni)
                bfr[ni] = *(const bf16x8*)(Bs + (wn * 64 + ni * 16 + l) * 64 + co);
            #pragma unroll
            for (int mi = 0; mi < 4; ++mi)
                #pragma unroll
                for (int ni = 0; ni < 4; ++ni)
                    acc[mi][ni] = MFMA(af[mi], bfr[ni], acc[mi][ni]);
        }
    }

    float* Pf = Cout + (size_t)blockIdx.z * M * N;
    #pragma unroll
    for (int mi = 0; mi < 4; ++mi)
        #pragma unroll
        for (int ni = 0; ni < 4; ++ni)
            #pragma unroll
            for (int r = 0; r < 4; ++r) {
                const int row = m0 + wm * 64 + mi * 16 + quad * 4 + r;
                const int col = n0 + wn * 64 + ni * 16 + l;
                Pf[(size_t)row * N + col] = acc[mi][ni][r];
            }
}

// split-K reduce: out[i] = p[i] + p[n+i]  (fp32, float4)
__global__ void reduce_add(const float* __restrict__ p, float* __restrict__ out, int n) {
    const int i = (blockIdx.x * 256 + threadIdx.x) * 4;
    float4 a = *(const float4*)(p + i);
    float4 b = *(const float4*)(p + n + i);
    float4 o = { a.x + b.x, a.y + b.y, a.z + b.z, a.w + b.w };
    *(float4*)(out + i) = o;
}

// ---------------------------------------------------------------------------
// Differential flash attention, R9: persistent cost-balanced blocks.
//  Grid = 768 = 3 blocks/CU resident (LDS 48K, VGPR ~84).
//   bid <  512 : one item, h = bid>>4, qb = 16 + (bid&15)   (17..32 tiles)
//   bid >= 512 : two items, h = j>>3, qb in {15-p, p}, p=j&7 (17 tiles total)
//  Per item: 64 q-rows, waves = sid(variant) x ks(kv-half), KVBLK=64 tiles,
//  double-buffered K/V staging, in-register P via cvt_pk + permlane swaps,
//  ks-partial O/csum merged via LDS, then epilogue. (R8 inner structure.)
// ---------------------------------------------------------------------------
__global__ __launch_bounds__(256, 3)
void diff_attn(const bf16* __restrict__ Q1, const bf16* __restrict__ K1,
               const bf16* __restrict__ Q2, const bf16* __restrict__ K2,
               const bf16* __restrict__ Vt, const float* __restrict__ lam_p,
               const float* __restrict__ subln_w, bf16* __restrict__ attn_out) {
    const int bid  = blockIdx.x;
    const int tid  = threadIdx.x;
    const int wave = tid >> 6, lane = tid & 63;
    const int sid  = wave >> 1, ks = wave & 1;        // variant, kv-half
    const int l    = lane & 15, quad = lane >> 4;

    __shared__ __align__(16) char smem[49152];

    const int rr  = tid >> 3;
    const int csw = ((tid & 7) ^ (rr & 7)) * 8;
    const int sw8 = l & 7;

    const int nIt = (bid < 512) ? 1 : 2;

    for (int it = 0; it < nIt; ++it) {
        int h, qb;
        if (bid < 512) { h = bid >> 4; qb = 16 + (bid & 15); }
        else {
            const int j = bid - 512;
            h = j >> 3;
            const int p = j & 7;
            qb = it ? p : (15 - p);
        }
        const int q0 = qb * 64;

        const bf16* Qh  = (sid ? Q2 : Q1) + ((size_t)h * S_LEN + q0) * HD;
        const bf16* K1g = K1 + (size_t)h * S_LEN * HD;
        const bf16* K2g = K2 + (size_t)h * S_LEN * HD;
        const bf16* Vtg = Vt + (size_t)h * HD * S_LEN;

        auto stage = [&](int kv, int bufb) {
            const bf16* k1p = K1g + (size_t)(kv + rr) * HD + csw;
            const bf16* k2p = K2g + (size_t)(kv + rr) * HD + csw;
            const bf16* vtp = Vtg + (size_t)rr * S_LEN + kv + csw;
            bf16* d1 = (bf16*)(smem + bufb)         + tid * 8;
            bf16* d2 = (bf16*)(smem + bufb + 8192)  + tid * 8;
            bf16* dv = (bf16*)(smem + bufb + 16384) + tid * 8;
            gld16(k1p,                       d1);
            gld16(k1p + (size_t)32 * HD,     d1 + 2048);
            gld16(k2p,                       d2);
            gld16(k2p + (size_t)32 * HD,     d2 + 2048);
            gld16(vtp,                       dv);
            gld16(vtp + (size_t)32 * S_LEN,  dv + 2048);
        };

        bf16x8 qf[4][2];
        #pragma unroll
        for (int g = 0; g < 4; ++g)
            #pragma unroll
            for (int dh = 0; dh < 2; ++dh)
                qf[g][dh] = *(const bf16x8*)(Qh + (g * 16 + l) * HD + dh * 32 + quad * 8);

        f32x4 O[4][4];                             // [g (q)][nd (d)] ks-partial
        #pragma unroll
        for (int g = 0; g < 4; ++g)
            #pragma unroll
            for (int nd = 0; nd < 4; ++nd)
                O[g][nd] = (f32x4){0.f, 0.f, 0.f, 0.f};
        float csum[4] = {0.f, 0.f, 0.f, 0.f};      // ks-partial row sums

        const int T = qb + 1;

        stage(0, 0);
        asm volatile("s_waitcnt vmcnt(0)" ::: "memory");
        __builtin_amdgcn_s_barrier();

        for (int t = 0; t < T; ++t) {
            const int bb = (t & 1) * 24576;
            if (t + 1 < T) stage((t + 1) * 64, 24576 - bb);

            {
                const bool diag = (t == qb);
                const bf16* Ksm = (const bf16*)(smem + bb + (sid ? 8192 : 0));
                const bf16* Vts = (const bf16*)(smem + bb + 16384);

                // K-frags: only this wave's kv-half (global mk = 2*ks + mk)
                bf16x8 ka[2][2];
                #pragma unroll
                for (int mk = 0; mk < 2; ++mk) {
                    const int krow = ((2 * ks + mk) * 16 + l) * 64;
                    ka[mk][0] = *(const bf16x8*)(Ksm + krow + ((quad ^ sw8) << 3));
                    ka[mk][1] = *(const bf16x8*)(Ksm + krow + (((4 + quad) ^ sw8) << 3));
                }
                // V-frags: only this wave's ks slot group
                bf16x8 vb[4];
                #pragma unroll
                for (int nd = 0; nd < 4; ++nd)
                    vb[nd] = *(const bf16x8*)(Vts + (nd * 16 + l) * 64 +
                                              ((((ks << 2) + quad) ^ sw8) << 3));

                __builtin_amdgcn_s_setprio(1);
                #pragma unroll
                for (int g = 0; g < 4; ++g) {
                    f32x4 c[2];
                    #pragma unroll
                    for (int mk = 0; mk < 2; ++mk) {
                        c[mk] = (f32x4){0.f, 0.f, 0.f, 0.f};
                        c[mk] = MFMA(ka[mk][0], qf[g][0], c[mk]);
                        c[mk] = MFMA(ka[mk][1], qf[g][1], c[mk]);
                    }
                    u32 dw[2][2];
                    float lsum = 0.f;
                    #pragma unroll
                    for (int mk = 0; mk < 2; ++mk) {
                        float p[4];
                        #pragma unroll
                        for (int r = 0; r < 4; ++r) {
                            p[r] = __builtin_amdgcn_exp2f(c[mk][r]);
                            if (diag && ((2 * ks + mk) * 16 + quad * 4 + r > g * 16 + l))
                                p[r] = 0.f;
                            lsum += p[r];
                        }
                        asm("v_cvt_pk_bf16_f32 %0, %1, %2" : "=v"(dw[mk][0]) : "v"(p[0]), "v"(p[1]));
                        asm("v_cvt_pk_bf16_f32 %0, %1, %2" : "=v"(dw[mk][1]) : "v"(p[2]), "v"(p[3]));
                    }
                    csum[g] += lsum;

                    u32 w0, w1, w2, w3;
                    pa_build(dw[0][0], dw[1][0], quad, w0, w2);
                    pa_build(dw[0][1], dw[1][1], quad, w1, w3);
                    u32x4 wv = {w0, w1, w2, w3};
                    bf16x8 pa;
                    __builtin_memcpy(&pa, &wv, 16);

                    #pragma unroll
                    for (int nd = 0; nd < 4; ++nd)
                        O[g][nd] = MFMA(pa, vb[nd], O[g][nd]);
                }
                __builtin_amdgcn_s_setprio(0);
            }

            asm volatile("s_waitcnt vmcnt(0)" ::: "memory");
            __builtin_amdgcn_s_barrier();
        }

        // ---------------- merge ks-halves ----------------
        __syncthreads();
        float* dO = (float*)(smem + sid * 17408);  // [lane][68] fp32
        float* dC = (float*)(smem + 34816 + sid * 1024);
        if (ks == 1) {
            #pragma unroll
            for (int g = 0; g < 4; ++g)
                #pragma unroll
                for (int nd = 0; nd < 4; ++nd)
                    *(f32x4*)(dO + lane * 68 + (g * 4 + nd) * 4) = O[g][nd];
            #pragma unroll
            for (int g = 0; g < 4; ++g) dC[g * 64 + lane] = csum[g];
        }
        __syncthreads();
        if (ks == 0) {
            #pragma unroll
            for (int g = 0; g < 4; ++g) {
                #pragma unroll
                for (int nd = 0; nd < 4; ++nd) {
                    f32x4 o = *(const f32x4*)(dO + lane * 68 + (g * 4 + nd) * 4);
                    O[g][nd] += o;
                }
                csum[g] += dC[g * 64 + lane];
            }
        }

        // full row-sums: reduce across quads
        #pragma unroll
        for (int g = 0; g < 4; ++g) {
            csum[g] += __shfl_xor(csum[g], 16, 64);
            csum[g] += __shfl_xor(csum[g], 32, 64);
        }
        __syncthreads();

        // ---------------- epilogue (ks==0 waves only) ----------------
        float* epi = (float*)smem;                 // [64][65] fp32

        if (sid == 1 && ks == 0) {
            const float lam = lam_p[0];
            #pragma unroll
            for (int mi = 0; mi < 4; ++mi)
                #pragma unroll
                for (int r = 0; r < 4; ++r) {
                    const float inv = lam / __shfl(csum[mi], quad * 4 + r, 64);
                    const int row = mi * 16 + quad * 4 + r;
                    #pragma unroll
                    for (int ni = 0; ni < 4; ++ni)
                        epi[row * 65 + ni * 16 + l] = O[mi][ni][r] * inv;
                }
        }
        __syncthreads();

        if (sid == 0 && ks == 0) {
            float sw[4];
            #pragma unroll
            for (int ni = 0; ni < 4; ++ni) sw[ni] = subln_w[ni * 16 + l];

            #pragma unroll
            for (int mi = 0; mi < 4; ++mi) {
                float inv1[4];
                #pragma unroll
                for (int r = 0; r < 4; ++r)
                    inv1[r] = 1.0f / __shfl(csum[mi], quad * 4 + r, 64);

                float v[4][4]; float ssq[4] = {0.f, 0.f, 0.f, 0.f};
                #pragma unroll
                for (int ni = 0; ni < 4; ++ni)
                    #pragma unroll
                    for (int r = 0; r < 4; ++r) {
                        const int row = mi * 16 + quad * 4 + r;
                        const float x = O[mi][ni][r] * inv1[r] - epi[row * 65 + ni * 16 + l];
                        v[ni][r] = x;
                        ssq[r] += x * x;
                    }
                #pragma unroll
                for (int r = 0; r < 4; ++r) {
                    float s = ssq[r];
                    s += __shfl_xor(s, 1, 64);
                    s += __shfl_xor(s, 2, 64);
                    s += __shfl_xor(s, 4, 64);
                    s += __shfl_xor(s, 8, 64);
                    ssq[r] = rsqrtf(s * (1.0f / 64.0f) + RMS_EPS) * ONE_MINUS_LAM_INIT;
                }
                #pragma unroll
                for (int ni = 0; ni < 4; ++ni)
                    #pragma unroll
                    for (int r = 0; r < 4; ++r) {
                        const int row = q0 + mi * 16 + quad * 4 + r;
                        attn_out[(size_t)row * HID_DIM + h * 64 + ni * 16 + l] =
                            (bf16)(v[ni][r] * ssq[r] * sw[ni]);
                    }
            }
        }
        __syncthreads();   // LDS safe for next item's staging
    }
}

// ---------------------------------------------------------------------------
// Workspace layout (bytes):
//   hsb   @ 0           8,388,608   hidden bf16
//   Wb    @ 8388608    41,943,040   Wq|Wk|Wv bf16
//   Wob   @ 50331648    8,388,608   Wo bf16
//   part  @ 58720256   33,554,432   O-proj split-K fp32 partials (2x)
//   Q1    @ 100663296   8,388,608
//   K1    @ 109051904   8,388,608
//   Q2    @ 117440512   8,388,608
//   K2    @ 125829120   8,388,608
//   Vt    @ 134217728   8,388,608
//   abuf  @ 142606336   8,388,608
//   lam   @ 150994944   4
// ---------------------------------------------------------------------------
extern "C" void kernel_launch(void* const* d_in, const int* in_sizes, int n_in,
                              void* d_out, int out_size, void* d_ws, size_t ws_size,
                              hipStream_t stream) {
    const float* hs  = (const float*)d_in[0];
    const float* Wq  = (const float*)d_in[1];
    const float* Wk  = (const float*)d_in[2];
    const float* Wv  = (const float*)d_in[3];
    const float* Wo  = (const float*)d_in[4];
    const float* lq1 = (const float*)d_in[5];
    const float* lk1 = (const float*)d_in[6];
    const float* lq2 = (const float*)d_in[7];
    const float* lk2 = (const float*)d_in[8];
    const float* slw = (const float*)d_in[9];

    if (ws_size < 151000000u) return;

    char* ws = (char*)d_ws;
    bf16*  hsb  = (bf16*)(ws);
    bf16*  Wb   = (bf16*)(ws + 8388608);
    bf16*  Wob  = (bf16*)(ws + 50331648);
    float* part = (float*)(ws + 58720256);
    bf16*  Q1b  = (bf16*)(ws + 100663296);
    bf16*  K1b  = (bf16*)(ws + 109051904);
    bf16*  Q2b  = (bf16*)(ws + 117440512);
    bf16*  K2b  = (bf16*)(ws + 125829120);
    bf16*  Vtb  = (bf16*)(ws + 134217728);
    bf16*  abuf = (bf16*)(ws + 142606336);
    float* lamp = (float*)(ws + 150994944);

    // 1) conversions + lambda
    cvt_all<<<14337, 256, 0, stream>>>(hs, Wq, Wk, Wv, Wo, lq1, lk1, lq2, lk2,
                                       hsb, Wb, Wob, lamp);

    // 2) fused QKV projection + RoPE + split + V transpose
    qkv_rope_gemm<<<dim3(QKV_N / 128, S_LEN / 128), 256, 0, stream>>>(
        hsb, Wb, Q1b, Q2b, K1b, K2b, Vtb);

    // 3) differential attention (persistent: 768 blocks = 3/CU)
    diff_attn<<<768, 256, 0, stream>>>(Q1b, K1b, Q2b, K2b, Vtb, lamp, slw, abuf);

    // 4) output projection, split-K=2 -> fp32 partials -> reduce to d_out
    gemm_bt_splitk<<<dim3(HID_DIM / 128, S_LEN / 128, 2), 256, 0, stream>>>(
        abuf, Wob, part, S_LEN, HID_DIM, HID_DIM, HID_DIM / 2);
    reduce_add<<<4096, 256, 0, stream>>>(part, (float*)d_out, S_LEN * HID_DIM);
}

// Round 4
// 343.807 us; speedup vs baseline: 1.1173x; 1.0421x over previous
//
#include <hip/hip_runtime.h>

// ---------------------------------------------------------------------------
// LlamaDifferentialAttentionBase on MI355X (gfx950)
// B=1, S=2048, HID=2048, H=32, D=64. All inputs fp32; output fp32.
// R10: diff_attn QBLK=128, 512 threads / 8 waves = qhalf x sid x ks.
//      Same per-wave inner math as R9 (4 g-groups, in-register P via
//      cvt_pk+permlane), but each staged KV tile serves 128 q-rows
//      (2x amortization of barrier/drain/stage). 256 blocks, each a
//      (qb, 15-qb) pair -> exactly 34 tiles/block, 1 block/CU, no tail.
//      h = bid&31 pins each head's 8 blocks to one XCD (K/V L2-resident).
// ---------------------------------------------------------------------------

typedef __bf16 bf16;
typedef __bf16 bf16x4 __attribute__((ext_vector_type(4)));
typedef __bf16 bf16x8 __attribute__((ext_vector_type(8)));
typedef float  f32x4  __attribute__((ext_vector_type(4)));
typedef unsigned int u32;
typedef u32 u32x2 __attribute__((ext_vector_type(2)));
typedef u32 u32x4 __attribute__((ext_vector_type(4)));

#define MFMA(a, b, c) __builtin_amdgcn_mfma_f32_16x16x32_bf16((a), (b), (c), 0, 0, 0)

#define S_LEN   2048
#define HID_DIM 2048
#define NHEAD   32
#define HD      64
#define QKV_N   10240                 // 4096 (q) + 4096 (k) + 2048 (v)
#define LAM_INIT 0.7836057665316245f  // 0.8 - 0.6*exp(-0.3*12)
#define ONE_MINUS_LAM_INIT 0.21639423346837553f
#define QSCALE  0.18033688011112042f  // (1/sqrt(64)) * log2(e)
#define RMS_EPS 1e-6f
#define L2T     0.4152410118609203f   // log2(10000)/32

// async global->LDS, 16B per lane; LDS dest = wave-uniform base + lane*16
__device__ __forceinline__ void gld16(const void* g, void* l) {
    __builtin_amdgcn_global_load_lds(
        (const __attribute__((address_space(1))) void*)g,
        (__attribute__((address_space(3))) void*)l, 16, 0, 0);
}

// Build PV A-operand dwords from QK^T accumulator dwords (validated R7-R9).
__device__ __forceinline__ void pa_build(u32 x, u32 y, int quad, u32& wlo, u32& whi) {
#if __has_builtin(__builtin_amdgcn_permlane32_swap) && __has_builtin(__builtin_amdgcn_permlane16_swap)
    u32x2 s = __builtin_amdgcn_permlane32_swap(x, y, false, false);
    u32x2 t = __builtin_amdgcn_permlane16_swap(s.x, s.y, false, false);
    wlo = t.x;
    whi = t.y;
#else
    const u32 x16 = (u32)__shfl_xor((int)x, 16, 64);
    const u32 x32 = (u32)__shfl_xor((int)x, 32, 64);
    const u32 x48 = (u32)__shfl_xor((int)x, 48, 64);
    const u32 y16 = (u32)__shfl_xor((int)y, 16, 64);
    const u32 y32 = (u32)__shfl_xor((int)y, 32, 64);
    const u32 y48 = (u32)__shfl_xor((int)y, 48, 64);
    wlo = (quad == 0) ? x   : (quad == 1) ? x48 : (quad == 2) ? y32 : y16;
    whi = (quad == 0) ? x16 : (quad == 1) ? x32 : (quad == 2) ? y48 : y;
#endif
}

// ---------------------------------------------------------------------------
// Fused fp32->bf16 for all 5 tensors + lambda scalar (last block).
// ---------------------------------------------------------------------------
__global__ void cvt_all(const float* __restrict__ hs, const float* __restrict__ Wq,
                        const float* __restrict__ Wk, const float* __restrict__ Wv,
                        const float* __restrict__ Wo,
                        const float* __restrict__ lq1, const float* __restrict__ lk1,
                        const float* __restrict__ lq2, const float* __restrict__ lk2,
                        bf16* __restrict__ hsb, bf16* __restrict__ Wb,
                        bf16* __restrict__ Wob, float* __restrict__ lam_out) {
    const int bid = blockIdx.x;
    if (bid >= 14336) {               // lambda block
        const int t = threadIdx.x;
        if (t < 64) {
            float a = lq1[t] * lk1[t];
            float b = lq2[t] * lk2[t];
            #pragma unroll
            for (int off = 32; off > 0; off >>= 1) {
                a += __shfl_xor(a, off, 64);
                b += __shfl_xor(b, off, 64);
            }
            if (t == 0) lam_out[0] = expf(a) - expf(b) + LAM_INIT;
        }
        return;
    }
    const float* src; bf16* dst; int off;
    if      (bid <  2048) { src = hs; dst = hsb;            off = bid;         }
    else if (bid <  6144) { src = Wq; dst = Wb;             off = bid - 2048;  }
    else if (bid < 10240) { src = Wk; dst = Wb +  8388608;  off = bid - 6144;  }
    else if (bid < 12288) { src = Wv; dst = Wb + 16777216;  off = bid - 10240; }
    else                  { src = Wo; dst = Wob;            off = bid - 12288; }
    const int i = off * 2048 + threadIdx.x * 8;
    float4 a = *(const float4*)(src + i);
    float4 b = *(const float4*)(src + i + 4);
    bf16x8 o = { (bf16)a.x, (bf16)a.y, (bf16)a.z, (bf16)a.w,
                 (bf16)b.x, (bf16)b.y, (bf16)b.z, (bf16)b.w };
    *(bf16x8*)(dst + i) = o;
}

// ---------------------------------------------------------------------------
// Fused QKV GEMM + RoPE + head split + V transpose. (unchanged from R9)
// ---------------------------------------------------------------------------
__global__ __launch_bounds__(256, 3)
void qkv_rope_gemm(const bf16* __restrict__ A, const bf16* __restrict__ B,
                   bf16* __restrict__ Q1, bf16* __restrict__ Q2,
                   bf16* __restrict__ K1, bf16* __restrict__ K2,
                   bf16* __restrict__ Vt) {
    __shared__ __align__(16) bf16 As[128 * 64];
    __shared__ __align__(16) bf16 Bs[128 * 64];
    const int tid  = threadIdx.x;
    const int wave = tid >> 6, lane = tid & 63;
    const int wm = wave >> 1, wn = wave & 1;      // wm: s-half, wn: d-half
    const int l = lane & 15, quad = lane >> 4;
    const int m0 = blockIdx.y * 128, n0 = blockIdx.x * 128;

    f32x4 acc[4][4];                              // [wi (d)][hi (s)]
    #pragma unroll
    for (int i = 0; i < 4; ++i)
        #pragma unroll
        for (int j = 0; j < 4; ++j) acc[i][j] = (f32x4){0.f, 0.f, 0.f, 0.f};

    const int rr  = tid >> 3;
    const int csw = ((tid & 7) ^ (rr & 7)) * 8;
    const bf16* Ag = A + (size_t)(m0 + rr) * HID_DIM + csw;
    const bf16* Bg = B + (size_t)(n0 + rr) * HID_DIM + csw;

    for (int kt = 0; kt < HID_DIM; kt += 64) {
        __syncthreads();
        #pragma unroll
        for (int j = 0; j < 4; ++j) {
            gld16(Ag + (size_t)(32 * j) * HID_DIM + kt, As + j * 2048 + tid * 8);
            gld16(Bg + (size_t)(32 * j) * HID_DIM + kt, Bs + j * 2048 + tid * 8);
        }
        __syncthreads();

        #pragma unroll
        for (int ks = 0; ks < 2; ++ks) {
            const int co = (((ks << 2) | quad) ^ (l & 7)) << 3;
            bf16x8 hf[4], wf[4];
            #pragma unroll
            for (int hi = 0; hi < 4; ++hi)
                hf[hi] = *(const bf16x8*)(As + (wm * 64 + hi * 16 + l) * 64 + co);
            #pragma unroll
            for (int wi = 0; wi < 4; ++wi)
                wf[wi] = *(const bf16x8*)(Bs + (wn * 64 + wi * 16 + l) * 64 + co);
            #pragma unroll
            for (int wi = 0; wi < 4; ++wi)
                #pragma unroll
                for (int hi = 0; hi < 4; ++hi)
                    acc[wi][hi] = MFMA(wf[wi], hf[hi], acc[wi][hi]);  // row=d, col=s
        }
    }

    // ---- epilogue: RoPE + store ----
    const int c = n0 + wn * 64;                   // global qkv column base
    const int sbase = m0 + wm * 64;
    bf16* dst; int off; float scale = 1.0f; bool isv = false;
    if      (c < 2048) { dst = Q1; off = c;        scale = QSCALE; }
    else if (c < 4096) { dst = Q2; off = c - 2048; scale = QSCALE; }
    else if (c < 6144) { dst = K1; off = c - 4096; }
    else if (c < 8192) { dst = K2; off = c - 6144; }
    else               { isv = true; off = c - 8192; }
    const int h = off >> 6;                       // off is 64-aligned

    if (!isv) {
        float invf[2][4];
        #pragma unroll
        for (int p = 0; p < 2; ++p)
            #pragma unroll
            for (int r = 0; r < 4; ++r)
                invf[p][r] = exp2f(-(float)(p * 16 + quad * 4 + r) * L2T);

        #pragma unroll
        for (int hi = 0; hi < 4; ++hi) {
            const float s = (float)(sbase + hi * 16 + l);
            float cs[2][4], sn[2][4];
            #pragma unroll
            for (int p = 0; p < 2; ++p)
                #pragma unroll
                for (int r = 0; r < 4; ++r) {
                    const float ang = s * invf[p][r];
                    cs[p][r] = __cosf(ang);
                    sn[p][r] = __sinf(ang);
                }
            bf16* rowp = dst + ((size_t)h * S_LEN + sbase + hi * 16 + l) * HD + quad * 4;
            #pragma unroll
            for (int wi = 0; wi < 4; ++wi) {
                const int p = wi & 1;
                const float sign = (wi < 2) ? -1.0f : 1.0f;
                bf16x4 o;
                #pragma unroll
                for (int r = 0; r < 4; ++r)
                    o[r] = (bf16)((acc[wi][hi][r] * cs[p][r] +
                                   sign * acc[wi ^ 2][hi][r] * sn[p][r]) * scale);
                *(bf16x4*)(rowp + wi * 16) = o;
            }
        }
    } else {
        #pragma unroll
        for (int wi = 0; wi < 4; ++wi)
            #pragma unroll
            for (int r = 0; r < 4; ++r) {
                bf16* vrow = Vt + ((size_t)h * HD + wi * 16 + quad * 4 + r) * S_LEN + sbase;
                #pragma unroll
                for (int hi = 0; hi < 4; ++hi)
                    vrow[hi * 16 + l] = (bf16)acc[wi][hi][r];
            }
    }
}

// ---------------------------------------------------------------------------
// GEMM: C[M,N] = A[M,K] * B[N,K]^T, split-K partials (O-proj). (unchanged)
// ---------------------------------------------------------------------------
__global__ __launch_bounds__(256, 3)
void gemm_bt_splitk(const bf16* __restrict__ A, const bf16* __restrict__ B,
                    float* __restrict__ Cout, int M, int N, int K_total, int K_part) {
    __shared__ __align__(16) bf16 As[128 * 64];
    __shared__ __align__(16) bf16 Bs[128 * 64];
    const int tid  = threadIdx.x;
    const int wave = tid >> 6, lane = tid & 63;
    const int wm = wave >> 1, wn = wave & 1;
    const int l = lane & 15, quad = lane >> 4;
    const int m0 = blockIdx.y * 128, n0 = blockIdx.x * 128;
    const int kz = blockIdx.z * K_part;

    f32x4 acc[4][4];
    #pragma unroll
    for (int i = 0; i < 4; ++i)
        #pragma unroll
        for (int j = 0; j < 4; ++j) acc[i][j] = (f32x4){0.f, 0.f, 0.f, 0.f};

    const int rr  = tid >> 3;
    const int csw = ((tid & 7) ^ (rr & 7)) * 8;
    const bf16* Ag = A + (size_t)(m0 + rr) * K_total + kz + csw;
    const bf16* Bg = B + (size_t)(n0 + rr) * K_total + kz + csw;

    for (int kt = 0; kt < K_part; kt += 64) {
        __syncthreads();
        #pragma unroll
        for (int j = 0; j < 4; ++j) {
            gld16(Ag + (size_t)(32 * j) * K_total + kt, As + j * 2048 + tid * 8);
            gld16(Bg + (size_t)(32 * j) * K_total + kt, Bs + j * 2048 + tid * 8);
        }
        __syncthreads();

        #pragma unroll
        for (int ks = 0; ks < 2; ++ks) {
            const int co = (((ks << 2) | quad) ^ (l & 7)) << 3;
            bf16x8 af[4], bfr[4];
            #pragma unroll
            for (int mi = 0; mi < 4; ++mi)
                af[mi] = *(const bf16x8*)(As + (wm * 64 + mi * 16 + l) * 64 + co);
            #pragma unroll
            for (int ni = 0; ni < 4; ++ni)
                bfr[ni] = *(const bf16x8*)(Bs + (wn * 64 + ni * 16 + l) * 64 + co);
            #pragma unroll
            for (int mi = 0; mi < 4; ++mi)
                #pragma unroll
                for (int ni = 0; ni < 4; ++ni)
                    acc[mi][ni] = MFMA(af[mi], bfr[ni], acc[mi][ni]);
        }
    }

    float* Pf = Cout + (size_t)blockIdx.z * M * N;
    #pragma unroll
    for (int mi = 0; mi < 4; ++mi)
        #pragma unroll
        for (int ni = 0; ni < 4; ++ni)
            #pragma unroll
            for (int r = 0; r < 4; ++r) {
                const int row = m0 + wm * 64 + mi * 16 + quad * 4 + r;
                const int col = n0 + wn * 64 + ni * 16 + l;
                Pf[(size_t)row * N + col] = acc[mi][ni][r];
            }
}

// split-K reduce: out[i] = p[i] + p[n+i]  (fp32, float4)
__global__ void reduce_add(const float* __restrict__ p, float* __restrict__ out, int n) {
    const int i = (blockIdx.x * 256 + threadIdx.x) * 4;
    float4 a = *(const float4*)(p + i);
    float4 b = *(const float4*)(p + n + i);
    float4 o = { a.x + b.x, a.y + b.y, a.z + b.z, a.w + b.w };
    *(float4*)(out + i) = o;
}

// ---------------------------------------------------------------------------
// Differential flash attention, R10: QBLK=128, 8 waves, perfect balance.
//  Grid 256 blocks (1/CU). Block b: head h=b&31 (8 blocks/head -> same XCD,
//  K/V L2-resident), pp=b>>5; items qb = {15-pp, pp} (34 tiles total).
//  Waves: qhalf(2) x sid(variant,2) x ks(kv-half,2); per wave 64 q-rows x
//  its variant x its kv-half = R9's exact inner loop (~150 regs,
//  2 waves/SIMD). Causality: wave diag tile tq = 2qb+qhalf; t>tq skipped
//  (qhalf=0's last tile only). ks-merge in 2 qhalf-rounds (LDS 48K).
// ---------------------------------------------------------------------------
__global__ __launch_bounds__(512, 2)
void diff_attn(const bf16* __restrict__ Q1, const bf16* __restrict__ K1,
               const bf16* __restrict__ Q2, const bf16* __restrict__ K2,
               const bf16* __restrict__ Vt, const float* __restrict__ lam_p,
               const float* __restrict__ subln_w, bf16* __restrict__ attn_out) {
    const int bid  = blockIdx.x;
    const int h    = bid & 31;
    const int pp   = bid >> 5;                    // 0..7
    const int tid  = threadIdx.x;
    const int wave = tid >> 6, lane = tid & 63;
    const int qhalf = wave >> 2, sid = (wave >> 1) & 1, ks = wave & 1;
    const int l = lane & 15, quad = lane >> 4;

    // 2 x 24576 B K/V double buffer {K1 8K | K2 8K | Vt 8K}.
    // Reused: merge dO @ sid*17408 (2x17408), dC @34816+sid*1024;
    // epi fp32 [128][65] @0 (33280 B).
    __shared__ __align__(16) char smem[49152];

    const bf16* K1g = K1 + (size_t)h * S_LEN * HD;
    const bf16* K2g = K2 + (size_t)h * S_LEN * HD;
    const bf16* Vtg = Vt + (size_t)h * HD * S_LEN;
    const bf16* Qv  = (sid ? Q2 : Q1) + (size_t)h * S_LEN * HD;

    const int rr  = tid >> 3;                     // 0..63 (512 threads)
    const int csw = ((tid & 7) ^ (rr & 7)) * 8;
    const int sw8 = l & 7;

    auto stage = [&](int kv, int bufb) {          // 3 gld16/thread = 24 KB
        gld16(K1g + (size_t)(kv + rr) * HD + csw,  (bf16*)(smem + bufb)         + tid * 8);
        gld16(K2g + (size_t)(kv + rr) * HD + csw,  (bf16*)(smem + bufb + 8192)  + tid * 8);
        gld16(Vtg + (size_t)rr * S_LEN + kv + csw, (bf16*)(smem + bufb + 16384) + tid * 8);
    };

    for (int it = 0; it < 2; ++it) {
        const int qb = it ? pp : (15 - pp);       // long item first
        const int q0 = qb * 128;
        const bf16* Qh = Qv + (size_t)(q0 + qhalf * 64) * HD;

        bf16x8 qf[4][2];
        #pragma unroll
        for (int g = 0; g < 4; ++g)
            #pragma unroll
            for (int dh = 0; dh < 2; ++dh)
                qf[g][dh] = *(const bf16x8*)(Qh + (g * 16 + l) * HD + dh * 32 + quad * 8);

        f32x4 O[4][4];                            // [g (q)][nd (d)] ks-partial
        #pragma unroll
        for (int g = 0; g < 4; ++g)
            #pragma unroll
            for (int nd = 0; nd < 4; ++nd)
                O[g][nd] = (f32x4){0.f, 0.f, 0.f, 0.f};
        float csum[4] = {0.f, 0.f, 0.f, 0.f};     // ks-partial row sums

        const int T  = 2 * qb + 2;
        const int tq = 2 * qb + qhalf;            // this wave's diag tile

        stage(0, 0);
        asm volatile("s_waitcnt vmcnt(0)" ::: "memory");
        __builtin_amdgcn_s_barrier();

        for (int t = 0; t < T; ++t) {
            const int bb = (t & 1) * 24576;
            if (t + 1 < T) stage((t + 1) * 64, 24576 - bb);

            if (t <= tq) {
                const bool diag = (t == tq);
                const bf16* Ksm = (const bf16*)(smem + bb + (sid ? 8192 : 0));
                const bf16* Vts = (const bf16*)(smem + bb + 16384);

                bf16x8 ka[2][2];
                #pragma unroll
                for (int mk = 0; mk < 2; ++mk) {
                    const int krow = ((2 * ks + mk) * 16 + l) * 64;
                    ka[mk][0] = *(const bf16x8*)(Ksm + krow + ((quad ^ sw8) << 3));
                    ka[mk][1] = *(const bf16x8*)(Ksm + krow + (((4 + quad) ^ sw8) << 3));
                }
                bf16x8 vb[4];
                #pragma unroll
                for (int nd = 0; nd < 4; ++nd)
                    vb[nd] = *(const bf16x8*)(Vts + (nd * 16 + l) * 64 +
                                              ((((ks << 2) + quad) ^ sw8) << 3));

                __builtin_amdgcn_s_setprio(1);
                #pragma unroll
                for (int g = 0; g < 4; ++g) {
                    f32x4 c[2];
                    #pragma unroll
                    for (int mk = 0; mk < 2; ++mk) {
                        c[mk] = (f32x4){0.f, 0.f, 0.f, 0.f};
                        c[mk] = MFMA(ka[mk][0], qf[g][0], c[mk]);
                        c[mk] = MFMA(ka[mk][1], qf[g][1], c[mk]);
                    }
                    u32 dw[2][2];
                    float lsum = 0.f;
                    #pragma unroll
                    for (int mk = 0; mk < 2; ++mk) {
                        float p[4];
                        #pragma unroll
                        for (int r = 0; r < 4; ++r) {
                            p[r] = __builtin_amdgcn_exp2f(c[mk][r]);
                            if (diag && ((2 * ks + mk) * 16 + quad * 4 + r > g * 16 + l))
                                p[r] = 0.f;
                            lsum += p[r];
                        }
                        asm("v_cvt_pk_bf16_f32 %0, %1, %2" : "=v"(dw[mk][0]) : "v"(p[0]), "v"(p[1]));
                        asm("v_cvt_pk_bf16_f32 %0, %1, %2" : "=v"(dw[mk][1]) : "v"(p[2]), "v"(p[3]));
                    }
                    csum[g] += lsum;

                    u32 w0, w1, w2, w3;
                    pa_build(dw[0][0], dw[1][0], quad, w0, w2);
                    pa_build(dw[0][1], dw[1][1], quad, w1, w3);
                    u32x4 wv = {w0, w1, w2, w3};
                    bf16x8 pa;
                    __builtin_memcpy(&pa, &wv, 16);

                    #pragma unroll
                    for (int nd = 0; nd < 4; ++nd)
                        O[g][nd] = MFMA(pa, vb[nd], O[g][nd]);
                }
                __builtin_amdgcn_s_setprio(0);
            }

            asm volatile("s_waitcnt vmcnt(0)" ::: "memory");
            __builtin_amdgcn_s_barrier();
        }

        // ---------------- merge ks-halves (2 rounds by qhalf) ----------------
        __syncthreads();
        #pragma unroll
        for (int round = 0; round < 2; ++round) {
            float* dO = (float*)(smem + sid * 17408);        // [64][68] fp32
            float* dC = (float*)(smem + 34816 + sid * 1024);
            if (qhalf == round && ks == 1) {
                #pragma unroll
                for (int g = 0; g < 4; ++g)
                    #pragma unroll
                    for (int nd = 0; nd < 4; ++nd)
                        *(f32x4*)(dO + lane * 68 + (g * 4 + nd) * 4) = O[g][nd];
                #pragma unroll
                for (int g = 0; g < 4; ++g) dC[g * 64 + lane] = csum[g];
            }
            __syncthreads();
            if (qhalf == round && ks == 0) {
                #pragma unroll
                for (int g = 0; g < 4; ++g) {
                    #pragma unroll
                    for (int nd = 0; nd < 4; ++nd)
                        O[g][nd] += *(const f32x4*)(dO + lane * 68 + (g * 4 + nd) * 4);
                    csum[g] += dC[g * 64 + lane];
                }
            }
            __syncthreads();
        }

        // full row-sums: reduce across quads
        #pragma unroll
        for (int g = 0; g < 4; ++g) {
            csum[g] += __shfl_xor(csum[g], 16, 64);
            csum[g] += __shfl_xor(csum[g], 32, 64);
        }

        // ---------------- epilogue (ks==0 waves only) ----------------
        float* epi = (float*)smem;                // [128][65] fp32

        if (sid == 1 && ks == 0) {
            const float lam = lam_p[0];
            #pragma unroll
            for (int mi = 0; mi < 4; ++mi)
                #pragma unroll
                for (int r = 0; r < 4; ++r) {
                    const float inv = lam / __shfl(csum[mi], quad * 4 + r, 64);
                    const int row = qhalf * 64 + mi * 16 + quad * 4 + r;
                    #pragma unroll
                    for (int ni = 0; ni < 4; ++ni)
                        epi[row * 65 + ni * 16 + l] = O[mi][ni][r] * inv;
                }
        }
        __syncthreads();

        if (sid == 0 && ks == 0) {
            float sw[4];
            #pragma unroll
            for (int ni = 0; ni < 4; ++ni) sw[ni] = subln_w[ni * 16 + l];

            #pragma unroll
            for (int mi = 0; mi < 4; ++mi) {
                float inv1[4];
                #pragma unroll
                for (int r = 0; r < 4; ++r)
                    inv1[r] = 1.0f / __shfl(csum[mi], quad * 4 + r, 64);

                float v[4][4]; float ssq[4] = {0.f, 0.f, 0.f, 0.f};
                #pragma unroll
                for (int ni = 0; ni < 4; ++ni)
                    #pragma unroll
                    for (int r = 0; r < 4; ++r) {
                        const int row = qhalf * 64 + mi * 16 + quad * 4 + r;
                        const float x = O[mi][ni][r] * inv1[r] - epi[row * 65 + ni * 16 + l];
                        v[ni][r] = x;
                        ssq[r] += x * x;
                    }
                #pragma unroll
                for (int r = 0; r < 4; ++r) {
                    float s = ssq[r];
                    s += __shfl_xor(s, 1, 64);
                    s += __shfl_xor(s, 2, 64);
                    s += __shfl_xor(s, 4, 64);
                    s += __shfl_xor(s, 8, 64);
                    ssq[r] = rsqrtf(s * (1.0f / 64.0f) + RMS_EPS) * ONE_MINUS_LAM_INIT;
                }
                #pragma unroll
                for (int ni = 0; ni < 4; ++ni)
                    #pragma unroll
                    for (int r = 0; r < 4; ++r) {
                        const int row = q0 + qhalf * 64 + mi * 16 + quad * 4 + r;
                        attn_out[(size_t)row * HID_DIM + h * 64 + ni * 16 + l] =
                            (bf16)(v[ni][r] * ssq[r] * sw[ni]);
                    }
            }
        }
        __syncthreads();   // LDS safe for next item's staging
    }
}

// ---------------------------------------------------------------------------
// Workspace layout (bytes):
//   hsb   @ 0           8,388,608   hidden bf16
//   Wb    @ 8388608    41,943,040   Wq|Wk|Wv bf16
//   Wob   @ 50331648    8,388,608   Wo bf16
//   part  @ 58720256   33,554,432   O-proj split-K fp32 partials (2x)
//   Q1    @ 100663296   8,388,608
//   K1    @ 109051904   8,388,608
//   Q2    @ 117440512   8,388,608
//   K2    @ 125829120   8,388,608
//   Vt    @ 134217728   8,388,608
//   abuf  @ 142606336   8,388,608
//   lam   @ 150994944   4
// ---------------------------------------------------------------------------
extern "C" void kernel_launch(void* const* d_in, const int* in_sizes, int n_in,
                              void* d_out, int out_size, void* d_ws, size_t ws_size,
                              hipStream_t stream) {
    const float* hs  = (const float*)d_in[0];
    const float* Wq  = (const float*)d_in[1];
    const float* Wk  = (const float*)d_in[2];
    const float* Wv  = (const float*)d_in[3];
    const float* Wo  = (const float*)d_in[4];
    const float* lq1 = (const float*)d_in[5];
    const float* lk1 = (const float*)d_in[6];
    const float* lq2 = (const float*)d_in[7];
    const float* lk2 = (const float*)d_in[8];
    const float* slw = (const float*)d_in[9];

    if (ws_size < 151000000u) return;

    char* ws = (char*)d_ws;
    bf16*  hsb  = (bf16*)(ws);
    bf16*  Wb   = (bf16*)(ws + 8388608);
    bf16*  Wob  = (bf16*)(ws + 50331648);
    float* part = (float*)(ws + 58720256);
    bf16*  Q1b  = (bf16*)(ws + 100663296);
    bf16*  K1b  = (bf16*)(ws + 109051904);
    bf16*  Q2b  = (bf16*)(ws + 117440512);
    bf16*  K2b  = (bf16*)(ws + 125829120);
    bf16*  Vtb  = (bf16*)(ws + 134217728);
    bf16*  abuf = (bf16*)(ws + 142606336);
    float* lamp = (float*)(ws + 150994944);

    // 1) conversions + lambda
    cvt_all<<<14337, 256, 0, stream>>>(hs, Wq, Wk, Wv, Wo, lq1, lk1, lq2, lk2,
                                       hsb, Wb, Wob, lamp);

    // 2) fused QKV projection + RoPE + split + V transpose
    qkv_rope_gemm<<<dim3(QKV_N / 128, S_LEN / 128), 256, 0, stream>>>(
        hsb, Wb, Q1b, Q2b, K1b, K2b, Vtb);

    // 3) differential attention (256 blocks x 512 threads, 1/CU, balanced)
    diff_attn<<<256, 512, 0, stream>>>(Q1b, K1b, Q2b, K2b, Vtb, lamp, slw, abuf);

    // 4) output projection, split-K=2 -> fp32 partials -> reduce to d_out
    gemm_bt_splitk<<<dim3(HID_DIM / 128, S_LEN / 128, 2), 256, 0, stream>>>(
        abuf, Wob, part, S_LEN, HID_DIM, HID_DIM, HID_DIM / 2);
    reduce_add<<<4096, 256, 0, stream>>>(part, (float*)d_out, S_LEN * HID_DIM);
}

// Round 5
// 343.233 us; speedup vs baseline: 1.1191x; 1.0017x over previous
//
#include <hip/hip_runtime.h>

// ---------------------------------------------------------------------------
// LlamaDifferentialAttentionBase on MI355X (gfx950)
// B=1, S=2048, HID=2048, H=32, D=64. All inputs fp32; output fp32.
// R11: diff_attn KVBLK=128 — stage 128 KV rows per LDS buffer (2x48K),
//      two 64-KV sub-tiles computed per barrier (sync events halved: 34->17
//      per block), unrolled so sub1's QK MFMAs overlap sub0's softmax VALU.
//      gemm_bt gets an XCD-rect block swizzle (each XCD owns a 4x8 tile
//      rectangle -> A+B panels ~L2-resident). Rest unchanged from R10.
// ---------------------------------------------------------------------------

typedef __bf16 bf16;
typedef __bf16 bf16x4 __attribute__((ext_vector_type(4)));
typedef __bf16 bf16x8 __attribute__((ext_vector_type(8)));
typedef float  f32x4  __attribute__((ext_vector_type(4)));
typedef unsigned int u32;
typedef u32 u32x2 __attribute__((ext_vector_type(2)));
typedef u32 u32x4 __attribute__((ext_vector_type(4)));

#define MFMA(a, b, c) __builtin_amdgcn_mfma_f32_16x16x32_bf16((a), (b), (c), 0, 0, 0)

#define S_LEN   2048
#define HID_DIM 2048
#define NHEAD   32
#define HD      64
#define QKV_N   10240                 // 4096 (q) + 4096 (k) + 2048 (v)
#define LAM_INIT 0.7836057665316245f  // 0.8 - 0.6*exp(-0.3*12)
#define ONE_MINUS_LAM_INIT 0.21639423346837553f
#define QSCALE  0.18033688011112042f  // (1/sqrt(64)) * log2(e)
#define RMS_EPS 1e-6f
#define L2T     0.4152410118609203f   // log2(10000)/32

// async global->LDS, 16B per lane; LDS dest = wave-uniform base + lane*16
__device__ __forceinline__ void gld16(const void* g, void* l) {
    __builtin_amdgcn_global_load_lds(
        (const __attribute__((address_space(1))) void*)g,
        (__attribute__((address_space(3))) void*)l, 16, 0, 0);
}

// Build PV A-operand dwords from QK^T accumulator dwords (validated R7-R10).
__device__ __forceinline__ void pa_build(u32 x, u32 y, int quad, u32& wlo, u32& whi) {
#if __has_builtin(__builtin_amdgcn_permlane32_swap) && __has_builtin(__builtin_amdgcn_permlane16_swap)
    u32x2 s = __builtin_amdgcn_permlane32_swap(x, y, false, false);
    u32x2 t = __builtin_amdgcn_permlane16_swap(s.x, s.y, false, false);
    wlo = t.x;
    whi = t.y;
#else
    const u32 x16 = (u32)__shfl_xor((int)x, 16, 64);
    const u32 x32 = (u32)__shfl_xor((int)x, 32, 64);
    const u32 x48 = (u32)__shfl_xor((int)x, 48, 64);
    const u32 y16 = (u32)__shfl_xor((int)y, 16, 64);
    const u32 y32 = (u32)__shfl_xor((int)y, 32, 64);
    const u32 y48 = (u32)__shfl_xor((int)y, 48, 64);
    wlo = (quad == 0) ? x   : (quad == 1) ? x48 : (quad == 2) ? y32 : y16;
    whi = (quad == 0) ? x16 : (quad == 1) ? x32 : (quad == 2) ? y48 : y;
#endif
}

// ---------------------------------------------------------------------------
// Fused fp32->bf16 for all 5 tensors + lambda scalar (last block).
// ---------------------------------------------------------------------------
__global__ void cvt_all(const float* __restrict__ hs, const float* __restrict__ Wq,
                        const float* __restrict__ Wk, const float* __restrict__ Wv,
                        const float* __restrict__ Wo,
                        const float* __restrict__ lq1, const float* __restrict__ lk1,
                        const float* __restrict__ lq2, const float* __restrict__ lk2,
                        bf16* __restrict__ hsb, bf16* __restrict__ Wb,
                        bf16* __restrict__ Wob, float* __restrict__ lam_out) {
    const int bid = blockIdx.x;
    if (bid >= 14336) {               // lambda block
        const int t = threadIdx.x;
        if (t < 64) {
            float a = lq1[t] * lk1[t];
            float b = lq2[t] * lk2[t];
            #pragma unroll
            for (int off = 32; off > 0; off >>= 1) {
                a += __shfl_xor(a, off, 64);
                b += __shfl_xor(b, off, 64);
            }
            if (t == 0) lam_out[0] = expf(a) - expf(b) + LAM_INIT;
        }
        return;
    }
    const float* src; bf16* dst; int off;
    if      (bid <  2048) { src = hs; dst = hsb;            off = bid;         }
    else if (bid <  6144) { src = Wq; dst = Wb;             off = bid - 2048;  }
    else if (bid < 10240) { src = Wk; dst = Wb +  8388608;  off = bid - 6144;  }
    else if (bid < 12288) { src = Wv; dst = Wb + 16777216;  off = bid - 10240; }
    else                  { src = Wo; dst = Wob;            off = bid - 12288; }
    const int i = off * 2048 + threadIdx.x * 8;
    float4 a = *(const float4*)(src + i);
    float4 b = *(const float4*)(src + i + 4);
    bf16x8 o = { (bf16)a.x, (bf16)a.y, (bf16)a.z, (bf16)a.w,
                 (bf16)b.x, (bf16)b.y, (bf16)b.z, (bf16)b.w };
    *(bf16x8*)(dst + i) = o;
}

// ---------------------------------------------------------------------------
// Fused QKV GEMM + RoPE + head split + V transpose. (unchanged from R10)
// ---------------------------------------------------------------------------
__global__ __launch_bounds__(256, 3)
void qkv_rope_gemm(const bf16* __restrict__ A, const bf16* __restrict__ B,
                   bf16* __restrict__ Q1, bf16* __restrict__ Q2,
                   bf16* __restrict__ K1, bf16* __restrict__ K2,
                   bf16* __restrict__ Vt) {
    __shared__ __align__(16) bf16 As[128 * 64];
    __shared__ __align__(16) bf16 Bs[128 * 64];
    const int tid  = threadIdx.x;
    const int wave = tid >> 6, lane = tid & 63;
    const int wm = wave >> 1, wn = wave & 1;      // wm: s-half, wn: d-half
    const int l = lane & 15, quad = lane >> 4;
    const int m0 = blockIdx.y * 128, n0 = blockIdx.x * 128;

    f32x4 acc[4][4];                              // [wi (d)][hi (s)]
    #pragma unroll
    for (int i = 0; i < 4; ++i)
        #pragma unroll
        for (int j = 0; j < 4; ++j) acc[i][j] = (f32x4){0.f, 0.f, 0.f, 0.f};

    const int rr  = tid >> 3;
    const int csw = ((tid & 7) ^ (rr & 7)) * 8;
    const bf16* Ag = A + (size_t)(m0 + rr) * HID_DIM + csw;
    const bf16* Bg = B + (size_t)(n0 + rr) * HID_DIM + csw;

    for (int kt = 0; kt < HID_DIM; kt += 64) {
        __syncthreads();
        #pragma unroll
        for (int j = 0; j < 4; ++j) {
            gld16(Ag + (size_t)(32 * j) * HID_DIM + kt, As + j * 2048 + tid * 8);
            gld16(Bg + (size_t)(32 * j) * HID_DIM + kt, Bs + j * 2048 + tid * 8);
        }
        __syncthreads();

        #pragma unroll
        for (int ks = 0; ks < 2; ++ks) {
            const int co = (((ks << 2) | quad) ^ (l & 7)) << 3;
            bf16x8 hf[4], wf[4];
            #pragma unroll
            for (int hi = 0; hi < 4; ++hi)
                hf[hi] = *(const bf16x8*)(As + (wm * 64 + hi * 16 + l) * 64 + co);
            #pragma unroll
            for (int wi = 0; wi < 4; ++wi)
                wf[wi] = *(const bf16x8*)(Bs + (wn * 64 + wi * 16 + l) * 64 + co);
            #pragma unroll
            for (int wi = 0; wi < 4; ++wi)
                #pragma unroll
                for (int hi = 0; hi < 4; ++hi)
                    acc[wi][hi] = MFMA(wf[wi], hf[hi], acc[wi][hi]);  // row=d, col=s
        }
    }

    // ---- epilogue: RoPE + store ----
    const int c = n0 + wn * 64;                   // global qkv column base
    const int sbase = m0 + wm * 64;
    bf16* dst; int off; float scale = 1.0f; bool isv = false;
    if      (c < 2048) { dst = Q1; off = c;        scale = QSCALE; }
    else if (c < 4096) { dst = Q2; off = c - 2048; scale = QSCALE; }
    else if (c < 6144) { dst = K1; off = c - 4096; }
    else if (c < 8192) { dst = K2; off = c - 6144; }
    else               { isv = true; off = c - 8192; }
    const int h = off >> 6;                       // off is 64-aligned

    if (!isv) {
        float invf[2][4];
        #pragma unroll
        for (int p = 0; p < 2; ++p)
            #pragma unroll
            for (int r = 0; r < 4; ++r)
                invf[p][r] = exp2f(-(float)(p * 16 + quad * 4 + r) * L2T);

        #pragma unroll
        for (int hi = 0; hi < 4; ++hi) {
            const float s = (float)(sbase + hi * 16 + l);
            float cs[2][4], sn[2][4];
            #pragma unroll
            for (int p = 0; p < 2; ++p)
                #pragma unroll
                for (int r = 0; r < 4; ++r) {
                    const float ang = s * invf[p][r];
                    cs[p][r] = __cosf(ang);
                    sn[p][r] = __sinf(ang);
                }
            bf16* rowp = dst + ((size_t)h * S_LEN + sbase + hi * 16 + l) * HD + quad * 4;
            #pragma unroll
            for (int wi = 0; wi < 4; ++wi) {
                const int p = wi & 1;
                const float sign = (wi < 2) ? -1.0f : 1.0f;
                bf16x4 o;
                #pragma unroll
                for (int r = 0; r < 4; ++r)
                    o[r] = (bf16)((acc[wi][hi][r] * cs[p][r] +
                                   sign * acc[wi ^ 2][hi][r] * sn[p][r]) * scale);
                *(bf16x4*)(rowp + wi * 16) = o;
            }
        }
    } else {
        #pragma unroll
        for (int wi = 0; wi < 4; ++wi)
            #pragma unroll
            for (int r = 0; r < 4; ++r) {
                bf16* vrow = Vt + ((size_t)h * HD + wi * 16 + quad * 4 + r) * S_LEN + sbase;
                #pragma unroll
                for (int hi = 0; hi < 4; ++hi)
                    vrow[hi * 16 + l] = (bf16)acc[wi][hi][r];
            }
    }
}

// ---------------------------------------------------------------------------
// GEMM: C[M,N] = A[M,K] * B[N,K]^T, split-K partials (O-proj).
// R11: XCD-rect swizzle — each XCD owns a 4(y) x 8(x) tile rectangle so its
// A-panels (2 MB) + B-panels (4 MB) stay L2-resident. Bijective per z.
// ---------------------------------------------------------------------------
__global__ __launch_bounds__(256, 3)
void gemm_bt_splitk(const bf16* __restrict__ A, const bf16* __restrict__ B,
                    float* __restrict__ Cout, int M, int N, int K_total, int K_part) {
    __shared__ __align__(16) bf16 As[128 * 64];
    __shared__ __align__(16) bf16 Bs[128 * 64];
    const int tid  = threadIdx.x;
    const int wave = tid >> 6, lane = tid & 63;
    const int wm = wave >> 1, wn = wave & 1;
    const int l = lane & 15, quad = lane >> 4;
    // XCD-rect remap: lin = x + 16y (dispatch order); xcd = lin&7 (HW round-
    // robin); XCD (yq,xh) owns rows [4yq,4yq+4) x cols [8xh,8xh+8).
    const int lin = blockIdx.y * 16 + blockIdx.x;
    const int xcd = lin & 7, j = lin >> 3;
    const int m0 = (((xcd >> 1) << 2) + (j & 3)) * 128;
    const int n0 = (((xcd & 1) << 3) + (j >> 2)) * 128;
    const int kz = blockIdx.z * K_part;

    f32x4 acc[4][4];
    #pragma unroll
    for (int i = 0; i < 4; ++i)
        #pragma unroll
        for (int j2 = 0; j2 < 4; ++j2) acc[i][j2] = (f32x4){0.f, 0.f, 0.f, 0.f};

    const int rr  = tid >> 3;
    const int csw = ((tid & 7) ^ (rr & 7)) * 8;
    const bf16* Ag = A + (size_t)(m0 + rr) * K_total + kz + csw;
    const bf16* Bg = B + (size_t)(n0 + rr) * K_total + kz + csw;

    for (int kt = 0; kt < K_part; kt += 64) {
        __syncthreads();
        #pragma unroll
        for (int jj = 0; jj < 4; ++jj) {
            gld16(Ag + (size_t)(32 * jj) * K_total + kt, As + jj * 2048 + tid * 8);
            gld16(Bg + (size_t)(32 * jj) * K_total + kt, Bs + jj * 2048 + tid * 8);
        }
        __syncthreads();

        #pragma unroll
        for (int ks = 0; ks < 2; ++ks) {
            const int co = (((ks << 2) | quad) ^ (l & 7)) << 3;
            bf16x8 af[4], bfr[4];
            #pragma unroll
            for (int mi = 0; mi < 4; ++mi)
                af[mi] = *(const bf16x8*)(As + (wm * 64 + mi * 16 + l) * 64 + co);
            #pragma unroll
            for (int ni = 0; ni < 4; ++ni)
                bfr[ni] = *(const bf16x8*)(Bs + (wn * 64 + ni * 16 + l) * 64 + co);
            #pragma unroll
            for (int mi = 0; mi < 4; ++mi)
                #pragma unroll
                for (int ni = 0; ni < 4; ++ni)
                    acc[mi][ni] = MFMA(af[mi], bfr[ni], acc[mi][ni]);
        }
    }

    float* Pf = Cout + (size_t)blockIdx.z * M * N;
    #pragma unroll
    for (int mi = 0; mi < 4; ++mi)
        #pragma unroll
        for (int ni = 0; ni < 4; ++ni)
            #pragma unroll
            for (int r = 0; r < 4; ++r) {
                const int row = m0 + wm * 64 + mi * 16 + quad * 4 + r;
                const int col = n0 + wn * 64 + ni * 16 + l;
                Pf[(size_t)row * N + col] = acc[mi][ni][r];
            }
}

// split-K reduce: out[i] = p[i] + p[n+i]  (fp32, float4)
__global__ void reduce_add(const float* __restrict__ p, float* __restrict__ out, int n) {
    const int i = (blockIdx.x * 256 + threadIdx.x) * 4;
    float4 a = *(const float4*)(p + i);
    float4 b = *(const float4*)(p + n + i);
    float4 o = { a.x + b.x, a.y + b.y, a.z + b.z, a.w + b.w };
    *(float4*)(out + i) = o;
}

// ---------------------------------------------------------------------------
// Differential flash attention, R11: QBLK=128, KVBLK=128 staging.
//  Grid 256 blocks (1/CU), 512 threads / 8 waves = qhalf x sid x ks.
//  LDS: 2 x 49152 double buffer, each {K1 16K | K2 16K | Vt 16K}, every
//  16K region = two [64][64] sub-tiles. One vmcnt(0)+barrier per 128 KV
//  rows (17 per block, was 34). The two 64-KV sub-computes are unrolled
//  back-to-back so sub1's QK MFMAs can overlap sub0's softmax VALU chain.
// ---------------------------------------------------------------------------
__global__ __launch_bounds__(512, 2)
void diff_attn(const bf16* __restrict__ Q1, const bf16* __restrict__ K1,
               const bf16* __restrict__ Q2, const bf16* __restrict__ K2,
               const bf16* __restrict__ Vt, const float* __restrict__ lam_p,
               const float* __restrict__ subln_w, bf16* __restrict__ attn_out) {
    const int bid  = blockIdx.x;
    const int h    = bid & 31;
    const int pp   = bid >> 5;                    // 0..7
    const int tid  = threadIdx.x;
    const int wave = tid >> 6, lane = tid & 63;
    const int qhalf = wave >> 2, sid = (wave >> 1) & 1, ks = wave & 1;
    const int l = lane & 15, quad = lane >> 4;

    // 2 x 49152 B K/V double buffer; merge/epilogue reuse the first 36864 B.
    __shared__ __align__(16) char smem[98304];

    const bf16* K1g = K1 + (size_t)h * S_LEN * HD;
    const bf16* K2g = K2 + (size_t)h * S_LEN * HD;
    const bf16* Vtg = Vt + (size_t)h * HD * S_LEN;
    const bf16* Qv  = (sid ? Q2 : Q1) + (size_t)h * S_LEN * HD;

    const int rr  = tid >> 3;                     // 0..63 (512 threads)
    const int csw = ((tid & 7) ^ (rr & 7)) * 8;
    const int sw8 = l & 7;

    auto stage = [&](int kv, int bufb) {          // kv 128-aligned; 48 KB
        #pragma unroll
        for (int s = 0; s < 2; ++s) {
            gld16(K1g + (size_t)(kv + s * 64 + rr) * HD + csw,
                  (bf16*)(smem + bufb)         + s * 4096 + tid * 8);
            gld16(K2g + (size_t)(kv + s * 64 + rr) * HD + csw,
                  (bf16*)(smem + bufb + 16384) + s * 4096 + tid * 8);
            gld16(Vtg + (size_t)rr * S_LEN + kv + s * 64 + csw,
                  (bf16*)(smem + bufb + 32768) + s * 4096 + tid * 8);
        }
    };

    for (int it = 0; it < 2; ++it) {
        const int qb = it ? pp : (15 - pp);       // long item first
        const int q0 = qb * 128;
        const bf16* Qh = Qv + (size_t)(q0 + qhalf * 64) * HD;

        bf16x8 qf[4][2];
        #pragma unroll
        for (int g = 0; g < 4; ++g)
            #pragma unroll
            for (int dh = 0; dh < 2; ++dh)
                qf[g][dh] = *(const bf16x8*)(Qh + (g * 16 + l) * HD + dh * 32 + quad * 8);

        f32x4 O[4][4];                            // [g (q)][nd (d)] ks-partial
        #pragma unroll
        for (int g = 0; g < 4; ++g)
            #pragma unroll
            for (int nd = 0; nd < 4; ++nd)
                O[g][nd] = (f32x4){0.f, 0.f, 0.f, 0.f};
        float csum[4] = {0.f, 0.f, 0.f, 0.f};     // ks-partial row sums

        const int nt = qb + 1;                    // 128-row staged steps
        const int tq = 2 * qb + qhalf;            // this wave's diag sub-tile

        stage(0, 0);
        asm volatile("s_waitcnt vmcnt(0)" ::: "memory");
        __builtin_amdgcn_s_barrier();

        for (int tt = 0; tt < nt; ++tt) {
            const int bb = (tt & 1) * 49152;
            if (tt + 1 < nt) stage((tt + 1) * 128, 49152 - bb);

            #pragma unroll
            for (int sub = 0; sub < 2; ++sub) {
                const int t64 = 2 * tt + sub;
                if (t64 <= tq) {
                    const bool diag = (t64 == tq);
                    const bf16* Ksm = (const bf16*)(smem + bb + (sid ? 16384 : 0))
                                      + sub * 4096;
                    const bf16* Vts = (const bf16*)(smem + bb + 32768) + sub * 4096;

                    bf16x8 ka[2][2];
                    #pragma unroll
                    for (int mk = 0; mk < 2; ++mk) {
                        const int krow = ((2 * ks + mk) * 16 + l) * 64;
                        ka[mk][0] = *(const bf16x8*)(Ksm + krow + ((quad ^ sw8) << 3));
                        ka[mk][1] = *(const bf16x8*)(Ksm + krow + (((4 + quad) ^ sw8) << 3));
                    }
                    bf16x8 vb[4];
                    #pragma unroll
                    for (int nd = 0; nd < 4; ++nd)
                        vb[nd] = *(const bf16x8*)(Vts + (nd * 16 + l) * 64 +
                                                  ((((ks << 2) + quad) ^ sw8) << 3));

                    __builtin_amdgcn_s_setprio(1);
                    #pragma unroll
                    for (int g = 0; g < 4; ++g) {
                        f32x4 c[2];
                        #pragma unroll
                        for (int mk = 0; mk < 2; ++mk) {
                            c[mk] = (f32x4){0.f, 0.f, 0.f, 0.f};
                            c[mk] = MFMA(ka[mk][0], qf[g][0], c[mk]);
                            c[mk] = MFMA(ka[mk][1], qf[g][1], c[mk]);
                        }
                        u32 dw[2][2];
                        float lsum = 0.f;
                        #pragma unroll
                        for (int mk = 0; mk < 2; ++mk) {
                            float p[4];
                            #pragma unroll
                            for (int r = 0; r < 4; ++r) {
                                p[r] = __builtin_amdgcn_exp2f(c[mk][r]);
                                if (diag && ((2 * ks + mk) * 16 + quad * 4 + r > g * 16 + l))
                                    p[r] = 0.f;
                                lsum += p[r];
                            }
                            asm("v_cvt_pk_bf16_f32 %0, %1, %2" : "=v"(dw[mk][0]) : "v"(p[0]), "v"(p[1]));
                            asm("v_cvt_pk_bf16_f32 %0, %1, %2" : "=v"(dw[mk][1]) : "v"(p[2]), "v"(p[3]));
                        }
                        csum[g] += lsum;

                        u32 w0, w1, w2, w3;
                        pa_build(dw[0][0], dw[1][0], quad, w0, w2);
                        pa_build(dw[0][1], dw[1][1], quad, w1, w3);
                        u32x4 wv = {w0, w1, w2, w3};
                        bf16x8 pa;
                        __builtin_memcpy(&pa, &wv, 16);

                        #pragma unroll
                        for (int nd = 0; nd < 4; ++nd)
                            O[g][nd] = MFMA(pa, vb[nd], O[g][nd]);
                    }
                    __builtin_amdgcn_s_setprio(0);
                }
            }

            asm volatile("s_waitcnt vmcnt(0)" ::: "memory");
            __builtin_amdgcn_s_barrier();
        }

        // ---------------- merge ks-halves (2 rounds by qhalf) ----------------
        __syncthreads();
        #pragma unroll
        for (int round = 0; round < 2; ++round) {
            float* dO = (float*)(smem + sid * 17408);        // [64][68] fp32
            float* dC = (float*)(smem + 34816 + sid * 1024);
            if (qhalf == round && ks == 1) {
                #pragma unroll
                for (int g = 0; g < 4; ++g)
                    #pragma unroll
                    for (int nd = 0; nd < 4; ++nd)
                        *(f32x4*)(dO + lane * 68 + (g * 4 + nd) * 4) = O[g][nd];
                #pragma unroll
                for (int g = 0; g < 4; ++g) dC[g * 64 + lane] = csum[g];
            }
            __syncthreads();
            if (qhalf == round && ks == 0) {
                #pragma unroll
                for (int g = 0; g < 4; ++g) {
                    #pragma unroll
                    for (int nd = 0; nd < 4; ++nd)
                        O[g][nd] += *(const f32x4*)(dO + lane * 68 + (g * 4 + nd) * 4);
                    csum[g] += dC[g * 64 + lane];
                }
            }
            __syncthreads();
        }

        // full row-sums: reduce across quads
        #pragma unroll
        for (int g = 0; g < 4; ++g) {
            csum[g] += __shfl_xor(csum[g], 16, 64);
            csum[g] += __shfl_xor(csum[g], 32, 64);
        }

        // ---------------- epilogue (ks==0 waves only) ----------------
        float* epi = (float*)smem;                // [128][65] fp32

        if (sid == 1 && ks == 0) {
            const float lam = lam_p[0];
            #pragma unroll
            for (int mi = 0; mi < 4; ++mi)
                #pragma unroll
                for (int r = 0; r < 4; ++r) {
                    const float inv = lam / __shfl(csum[mi], quad * 4 + r, 64);
                    const int row = qhalf * 64 + mi * 16 + quad * 4 + r;
                    #pragma unroll
                    for (int ni = 0; ni < 4; ++ni)
                        epi[row * 65 + ni * 16 + l] = O[mi][ni][r] * inv;
                }
        }
        __syncthreads();

        if (sid == 0 && ks == 0) {
            float sw[4];
            #pragma unroll
            for (int ni = 0; ni < 4; ++ni) sw[ni] = subln_w[ni * 16 + l];

            #pragma unroll
            for (int mi = 0; mi < 4; ++mi) {
                float inv1[4];
                #pragma unroll
                for (int r = 0; r < 4; ++r)
                    inv1[r] = 1.0f / __shfl(csum[mi], quad * 4 + r, 64);

                float v[4][4]; float ssq[4] = {0.f, 0.f, 0.f, 0.f};
                #pragma unroll
                for (int ni = 0; ni < 4; ++ni)
                    #pragma unroll
                    for (int r = 0; r < 4; ++r) {
                        const int row = qhalf * 64 + mi * 16 + quad * 4 + r;
                        const float x = O[mi][ni][r] * inv1[r] - epi[row * 65 + ni * 16 + l];
                        v[ni][r] = x;
                        ssq[r] += x * x;
                    }
                #pragma unroll
                for (int r = 0; r < 4; ++r) {
                    float s = ssq[r];
                    s += __shfl_xor(s, 1, 64);
                    s += __shfl_xor(s, 2, 64);
                    s += __shfl_xor(s, 4, 64);
                    s += __shfl_xor(s, 8, 64);
                    ssq[r] = rsqrtf(s * (1.0f / 64.0f) + RMS_EPS) * ONE_MINUS_LAM_INIT;
                }
                #pragma unroll
                for (int ni = 0; ni < 4; ++ni)
                    #pragma unroll
                    for (int r = 0; r < 4; ++r) {
                        const int row = q0 + qhalf * 64 + mi * 16 + quad * 4 + r;
                        attn_out[(size_t)row * HID_DIM + h * 64 + ni * 16 + l] =
                            (bf16)(v[ni][r] * ssq[r] * sw[ni]);
                    }
            }
        }
        __syncthreads();   // LDS safe for next item's staging
    }
}

// ---------------------------------------------------------------------------
// Workspace layout (bytes):
//   hsb   @ 0           8,388,608   hidden bf16
//   Wb    @ 8388608    41,943,040   Wq|Wk|Wv bf16
//   Wob   @ 50331648    8,388,608   Wo bf16
//   part  @ 58720256   33,554,432   O-proj split-K fp32 partials (2x)
//   Q1    @ 100663296   8,388,608
//   K1    @ 109051904   8,388,608
//   Q2    @ 117440512   8,388,608
//   K2    @ 125829120   8,388,608
//   Vt    @ 134217728   8,388,608
//   abuf  @ 142606336   8,388,608
//   lam   @ 150994944   4
// ---------------------------------------------------------------------------
extern "C" void kernel_launch(void* const* d_in, const int* in_sizes, int n_in,
                              void* d_out, int out_size, void* d_ws, size_t ws_size,
                              hipStream_t stream) {
    const float* hs  = (const float*)d_in[0];
    const float* Wq  = (const float*)d_in[1];
    const float* Wk  = (const float*)d_in[2];
    const float* Wv  = (const float*)d_in[3];
    const float* Wo  = (const float*)d_in[4];
    const float* lq1 = (const float*)d_in[5];
    const float* lk1 = (const float*)d_in[6];
    const float* lq2 = (const float*)d_in[7];
    const float* lk2 = (const float*)d_in[8];
    const float* slw = (const float*)d_in[9];

    if (ws_size < 151000000u) return;

    char* ws = (char*)d_ws;
    bf16*  hsb  = (bf16*)(ws);
    bf16*  Wb   = (bf16*)(ws + 8388608);
    bf16*  Wob  = (bf16*)(ws + 50331648);
    float* part = (float*)(ws + 58720256);
    bf16*  Q1b  = (bf16*)(ws + 100663296);
    bf16*  K1b  = (bf16*)(ws + 109051904);
    bf16*  Q2b  = (bf16*)(ws + 117440512);
    bf16*  K2b  = (bf16*)(ws + 125829120);
    bf16*  Vtb  = (bf16*)(ws + 134217728);
    bf16*  abuf = (bf16*)(ws + 142606336);
    float* lamp = (float*)(ws + 150994944);

    // 1) conversions + lambda
    cvt_all<<<14337, 256, 0, stream>>>(hs, Wq, Wk, Wv, Wo, lq1, lk1, lq2, lk2,
                                       hsb, Wb, Wob, lamp);

    // 2) fused QKV projection + RoPE + split + V transpose
    qkv_rope_gemm<<<dim3(QKV_N / 128, S_LEN / 128), 256, 0, stream>>>(
        hsb, Wb, Q1b, Q2b, K1b, K2b, Vtb);

    // 3) differential attention (256 blocks x 512 threads, KVBLK=128)
    diff_attn<<<256, 512, 0, stream>>>(Q1b, K1b, Q2b, K2b, Vtb, lamp, slw, abuf);

    // 4) output projection, split-K=2 -> fp32 partials -> reduce to d_out
    gemm_bt_splitk<<<dim3(HID_DIM / 128, S_LEN / 128, 2), 256, 0, stream>>>(
        abuf, Wob, part, S_LEN, HID_DIM, HID_DIM, HID_DIM / 2);
    reduce_add<<<4096, 256, 0, stream>>>(part, (float*)d_out, S_LEN * HID_DIM);
}

// Round 6
// 341.153 us; speedup vs baseline: 1.1259x; 1.0061x over previous
//
#include <hip/hip_runtime.h>

// ---------------------------------------------------------------------------
// LlamaDifferentialAttentionBase on MI355X (gfx950)
// B=1, S=2048, HID=2048, H=32, D=64. All inputs fp32; output fp32.
// R12: (a) O-projection split-K removed — gemm_bt writes d_out fp32 directly
//      (reduce_add kernel + 67 MB of partial traffic eliminated; grid 256 =
//      exactly 1 block/CU, per-CU work unchanged).
//      (b) diff_attn causal mask hoisted to a wave-uniform branch: clean
//      (mask-free) path for ~94% of subtiles, masked path only on the diag
//      subtile. Everything else unchanged from R11.
// ---------------------------------------------------------------------------

typedef __bf16 bf16;
typedef __bf16 bf16x4 __attribute__((ext_vector_type(4)));
typedef __bf16 bf16x8 __attribute__((ext_vector_type(8)));
typedef float  f32x4  __attribute__((ext_vector_type(4)));
typedef unsigned int u32;
typedef u32 u32x2 __attribute__((ext_vector_type(2)));
typedef u32 u32x4 __attribute__((ext_vector_type(4)));

#define MFMA(a, b, c) __builtin_amdgcn_mfma_f32_16x16x32_bf16((a), (b), (c), 0, 0, 0)

#define S_LEN   2048
#define HID_DIM 2048
#define NHEAD   32
#define HD      64
#define QKV_N   10240                 // 4096 (q) + 4096 (k) + 2048 (v)
#define LAM_INIT 0.7836057665316245f  // 0.8 - 0.6*exp(-0.3*12)
#define ONE_MINUS_LAM_INIT 0.21639423346837553f
#define QSCALE  0.18033688011112042f  // (1/sqrt(64)) * log2(e)
#define RMS_EPS 1e-6f
#define L2T     0.4152410118609203f   // log2(10000)/32

// async global->LDS, 16B per lane; LDS dest = wave-uniform base + lane*16
__device__ __forceinline__ void gld16(const void* g, void* l) {
    __builtin_amdgcn_global_load_lds(
        (const __attribute__((address_space(1))) void*)g,
        (__attribute__((address_space(3))) void*)l, 16, 0, 0);
}

// Build PV A-operand dwords from QK^T accumulator dwords (validated R7-R11).
__device__ __forceinline__ void pa_build(u32 x, u32 y, int quad, u32& wlo, u32& whi) {
#if __has_builtin(__builtin_amdgcn_permlane32_swap) && __has_builtin(__builtin_amdgcn_permlane16_swap)
    u32x2 s = __builtin_amdgcn_permlane32_swap(x, y, false, false);
    u32x2 t = __builtin_amdgcn_permlane16_swap(s.x, s.y, false, false);
    wlo = t.x;
    whi = t.y;
#else
    const u32 x16 = (u32)__shfl_xor((int)x, 16, 64);
    const u32 x32 = (u32)__shfl_xor((int)x, 32, 64);
    const u32 x48 = (u32)__shfl_xor((int)x, 48, 64);
    const u32 y16 = (u32)__shfl_xor((int)y, 16, 64);
    const u32 y32 = (u32)__shfl_xor((int)y, 32, 64);
    const u32 y48 = (u32)__shfl_xor((int)y, 48, 64);
    wlo = (quad == 0) ? x   : (quad == 1) ? x48 : (quad == 2) ? y32 : y16;
    whi = (quad == 0) ? x16 : (quad == 1) ? x32 : (quad == 2) ? y48 : y;
#endif
}

// ---------------------------------------------------------------------------
// Fused fp32->bf16 for all 5 tensors + lambda scalar (last block).
// ---------------------------------------------------------------------------
__global__ void cvt_all(const float* __restrict__ hs, const float* __restrict__ Wq,
                        const float* __restrict__ Wk, const float* __restrict__ Wv,
                        const float* __restrict__ Wo,
                        const float* __restrict__ lq1, const float* __restrict__ lk1,
                        const float* __restrict__ lq2, const float* __restrict__ lk2,
                        bf16* __restrict__ hsb, bf16* __restrict__ Wb,
                        bf16* __restrict__ Wob, float* __restrict__ lam_out) {
    const int bid = blockIdx.x;
    if (bid >= 14336) {               // lambda block
        const int t = threadIdx.x;
        if (t < 64) {
            float a = lq1[t] * lk1[t];
            float b = lq2[t] * lk2[t];
            #pragma unroll
            for (int off = 32; off > 0; off >>= 1) {
                a += __shfl_xor(a, off, 64);
                b += __shfl_xor(b, off, 64);
            }
            if (t == 0) lam_out[0] = expf(a) - expf(b) + LAM_INIT;
        }
        return;
    }
    const float* src; bf16* dst; int off;
    if      (bid <  2048) { src = hs; dst = hsb;            off = bid;         }
    else if (bid <  6144) { src = Wq; dst = Wb;             off = bid - 2048;  }
    else if (bid < 10240) { src = Wk; dst = Wb +  8388608;  off = bid - 6144;  }
    else if (bid < 12288) { src = Wv; dst = Wb + 16777216;  off = bid - 10240; }
    else                  { src = Wo; dst = Wob;            off = bid - 12288; }
    const int i = off * 2048 + threadIdx.x * 8;
    float4 a = *(const float4*)(src + i);
    float4 b = *(const float4*)(src + i + 4);
    bf16x8 o = { (bf16)a.x, (bf16)a.y, (bf16)a.z, (bf16)a.w,
                 (bf16)b.x, (bf16)b.y, (bf16)b.z, (bf16)b.w };
    *(bf16x8*)(dst + i) = o;
}

// ---------------------------------------------------------------------------
// Fused QKV GEMM + RoPE + head split + V transpose. (unchanged)
// ---------------------------------------------------------------------------
__global__ __launch_bounds__(256, 3)
void qkv_rope_gemm(const bf16* __restrict__ A, const bf16* __restrict__ B,
                   bf16* __restrict__ Q1, bf16* __restrict__ Q2,
                   bf16* __restrict__ K1, bf16* __restrict__ K2,
                   bf16* __restrict__ Vt) {
    __shared__ __align__(16) bf16 As[128 * 64];
    __shared__ __align__(16) bf16 Bs[128 * 64];
    const int tid  = threadIdx.x;
    const int wave = tid >> 6, lane = tid & 63;
    const int wm = wave >> 1, wn = wave & 1;      // wm: s-half, wn: d-half
    const int l = lane & 15, quad = lane >> 4;
    const int m0 = blockIdx.y * 128, n0 = blockIdx.x * 128;

    f32x4 acc[4][4];                              // [wi (d)][hi (s)]
    #pragma unroll
    for (int i = 0; i < 4; ++i)
        #pragma unroll
        for (int j = 0; j < 4; ++j) acc[i][j] = (f32x4){0.f, 0.f, 0.f, 0.f};

    const int rr  = tid >> 3;
    const int csw = ((tid & 7) ^ (rr & 7)) * 8;
    const bf16* Ag = A + (size_t)(m0 + rr) * HID_DIM + csw;
    const bf16* Bg = B + (size_t)(n0 + rr) * HID_DIM + csw;

    for (int kt = 0; kt < HID_DIM; kt += 64) {
        __syncthreads();
        #pragma unroll
        for (int j = 0; j < 4; ++j) {
            gld16(Ag + (size_t)(32 * j) * HID_DIM + kt, As + j * 2048 + tid * 8);
            gld16(Bg + (size_t)(32 * j) * HID_DIM + kt, Bs + j * 2048 + tid * 8);
        }
        __syncthreads();

        #pragma unroll
        for (int ks = 0; ks < 2; ++ks) {
            const int co = (((ks << 2) | quad) ^ (l & 7)) << 3;
            bf16x8 hf[4], wf[4];
            #pragma unroll
            for (int hi = 0; hi < 4; ++hi)
                hf[hi] = *(const bf16x8*)(As + (wm * 64 + hi * 16 + l) * 64 + co);
            #pragma unroll
            for (int wi = 0; wi < 4; ++wi)
                wf[wi] = *(const bf16x8*)(Bs + (wn * 64 + wi * 16 + l) * 64 + co);
            #pragma unroll
            for (int wi = 0; wi < 4; ++wi)
                #pragma unroll
                for (int hi = 0; hi < 4; ++hi)
                    acc[wi][hi] = MFMA(wf[wi], hf[hi], acc[wi][hi]);  // row=d, col=s
        }
    }

    // ---- epilogue: RoPE + store ----
    const int c = n0 + wn * 64;                   // global qkv column base
    const int sbase = m0 + wm * 64;
    bf16* dst; int off; float scale = 1.0f; bool isv = false;
    if      (c < 2048) { dst = Q1; off = c;        scale = QSCALE; }
    else if (c < 4096) { dst = Q2; off = c - 2048; scale = QSCALE; }
    else if (c < 6144) { dst = K1; off = c - 4096; }
    else if (c < 8192) { dst = K2; off = c - 6144; }
    else               { isv = true; off = c - 8192; }
    const int h = off >> 6;                       // off is 64-aligned

    if (!isv) {
        float invf[2][4];
        #pragma unroll
        for (int p = 0; p < 2; ++p)
            #pragma unroll
            for (int r = 0; r < 4; ++r)
                invf[p][r] = exp2f(-(float)(p * 16 + quad * 4 + r) * L2T);

        #pragma unroll
        for (int hi = 0; hi < 4; ++hi) {
            const float s = (float)(sbase + hi * 16 + l);
            float cs[2][4], sn[2][4];
            #pragma unroll
            for (int p = 0; p < 2; ++p)
                #pragma unroll
                for (int r = 0; r < 4; ++r) {
                    const float ang = s * invf[p][r];
                    cs[p][r] = __cosf(ang);
                    sn[p][r] = __sinf(ang);
                }
            bf16* rowp = dst + ((size_t)h * S_LEN + sbase + hi * 16 + l) * HD + quad * 4;
            #pragma unroll
            for (int wi = 0; wi < 4; ++wi) {
                const int p = wi & 1;
                const float sign = (wi < 2) ? -1.0f : 1.0f;
                bf16x4 o;
                #pragma unroll
                for (int r = 0; r < 4; ++r)
                    o[r] = (bf16)((acc[wi][hi][r] * cs[p][r] +
                                   sign * acc[wi ^ 2][hi][r] * sn[p][r]) * scale);
                *(bf16x4*)(rowp + wi * 16) = o;
            }
        }
    } else {
        #pragma unroll
        for (int wi = 0; wi < 4; ++wi)
            #pragma unroll
            for (int r = 0; r < 4; ++r) {
                bf16* vrow = Vt + ((size_t)h * HD + wi * 16 + quad * 4 + r) * S_LEN + sbase;
                #pragma unroll
                for (int hi = 0; hi < 4; ++hi)
                    vrow[hi * 16 + l] = (bf16)acc[wi][hi][r];
            }
    }
}

// ---------------------------------------------------------------------------
// GEMM: C[M,N] = A[M,K] * B[N,K]^T, full-K, direct fp32 output (O-proj).
// Grid 16x16 = 256 blocks = 1 block/CU. XCD-rect swizzle: each XCD owns a
// 4(m) x 8(n) tile rectangle (A 2MB + B 4MB ~ L2-resident).
// ---------------------------------------------------------------------------
__global__ __launch_bounds__(256, 3)
void gemm_bt(const bf16* __restrict__ A, const bf16* __restrict__ B,
             float* __restrict__ C, int M, int N, int K) {
    __shared__ __align__(16) bf16 As[128 * 64];
    __shared__ __align__(16) bf16 Bs[128 * 64];
    const int tid  = threadIdx.x;
    const int wave = tid >> 6, lane = tid & 63;
    const int wm = wave >> 1, wn = wave & 1;
    const int l = lane & 15, quad = lane >> 4;
    const int lin = blockIdx.y * 16 + blockIdx.x;
    const int xcd = lin & 7, j = lin >> 3;
    const int m0 = (((xcd >> 1) << 2) + (j & 3)) * 128;
    const int n0 = (((xcd & 1) << 3) + (j >> 2)) * 128;

    f32x4 acc[4][4];
    #pragma unroll
    for (int i = 0; i < 4; ++i)
        #pragma unroll
        for (int j2 = 0; j2 < 4; ++j2) acc[i][j2] = (f32x4){0.f, 0.f, 0.f, 0.f};

    const int rr  = tid >> 3;
    const int csw = ((tid & 7) ^ (rr & 7)) * 8;
    const bf16* Ag = A + (size_t)(m0 + rr) * K + csw;
    const bf16* Bg = B + (size_t)(n0 + rr) * K + csw;

    for (int kt = 0; kt < K; kt += 64) {
        __syncthreads();
        #pragma unroll
        for (int jj = 0; jj < 4; ++jj) {
            gld16(Ag + (size_t)(32 * jj) * K + kt, As + jj * 2048 + tid * 8);
            gld16(Bg + (size_t)(32 * jj) * K + kt, Bs + jj * 2048 + tid * 8);
        }
        __syncthreads();

        #pragma unroll
        for (int ks = 0; ks < 2; ++ks) {
            const int co = (((ks << 2) | quad) ^ (l & 7)) << 3;
            bf16x8 af[4], bfr[4];
            #pragma unroll
            for (int mi = 0; mi < 4; ++mi)
                af[mi] = *(const bf16x8*)(As + (wm * 64 + mi * 16 + l) * 64 + co);
            #pragma unroll
            for (int ni = 0; ni < 4; ++ni)
                bfr[ni] = *(const bf16x8*)(Bs + (wn * 64 + ni * 16 + l) * 64 + co);
            #pragma unroll
            for (int mi = 0; mi < 4; ++mi)
                #pragma unroll
                for (int ni = 0; ni < 4; ++ni)
                    acc[mi][ni] = MFMA(af[mi], bfr[ni], acc[mi][ni]);
        }
    }

    #pragma unroll
    for (int mi = 0; mi < 4; ++mi)
        #pragma unroll
        for (int ni = 0; ni < 4; ++ni)
            #pragma unroll
            for (int r = 0; r < 4; ++r) {
                const int row = m0 + wm * 64 + mi * 16 + quad * 4 + r;
                const int col = n0 + wn * 64 + ni * 16 + l;
                C[(size_t)row * N + col] = acc[mi][ni][r];
            }
}

// ---------------------------------------------------------------------------
// Differential flash attention, R12: QBLK=128, KVBLK=128, uniform diag branch.
//  Grid 256 blocks (1/CU), 512 threads / 8 waves = qhalf x sid x ks.
//  The 64-KV subtile core is instantiated twice via macro: DIAGF=0 (clean,
//  no mask VALU) for all interior subtiles, DIAGF=1 only on the wave's
//  diagonal subtile. Branch condition is wave-uniform -> s_cbranch.
// ---------------------------------------------------------------------------
#define ATTN_CORE(DIAGF)                                                      \
    {                                                                         \
        _Pragma("unroll")                                                     \
        for (int g = 0; g < 4; ++g) {                                         \
            f32x4 c[2];                                                       \
            _Pragma("unroll")                                                 \
            for (int mk = 0; mk < 2; ++mk) {                                  \
                c[mk] = (f32x4){0.f, 0.f, 0.f, 0.f};                          \
                c[mk] = MFMA(ka[mk][0], qf[g][0], c[mk]);                     \
                c[mk] = MFMA(ka[mk][1], qf[g][1], c[mk]);                     \
            }                                                                 \
            u32 dw[2][2];                                                     \
            float lsum = 0.f;                                                 \
            _Pragma("unroll")                                                 \
            for (int mk = 0; mk < 2; ++mk) {                                  \
                float p[4];                                                   \
                _Pragma("unroll")                                             \
                for (int r = 0; r < 4; ++r) {                                 \
                    p[r] = __builtin_amdgcn_exp2f(c[mk][r]);                  \
                    if (DIAGF && ((2 * ks + mk) * 16 + quad * 4 + r > g * 16 + l)) \
                        p[r] = 0.f;                                           \
                    lsum += p[r];                                             \
                }                                                             \
                asm("v_cvt_pk_bf16_f32 %0, %1, %2" : "=v"(dw[mk][0]) : "v"(p[0]), "v"(p[1])); \
                asm("v_cvt_pk_bf16_f32 %0, %1, %2" : "=v"(dw[mk][1]) : "v"(p[2]), "v"(p[3])); \
            }                                                                 \
            csum[g] += lsum;                                                  \
            u32 w0, w1, w2, w3;                                               \
            pa_build(dw[0][0], dw[1][0], quad, w0, w2);                       \
            pa_build(dw[0][1], dw[1][1], quad, w1, w3);                       \
            u32x4 wv = {w0, w1, w2, w3};                                      \
            bf16x8 pa;                                                        \
            __builtin_memcpy(&pa, &wv, 16);                                   \
            _Pragma("unroll")                                                 \
            for (int nd = 0; nd < 4; ++nd)                                    \
                O[g][nd] = MFMA(pa, vb[nd], O[g][nd]);                        \
        }                                                                     \
    }

__global__ __launch_bounds__(512, 2)
void diff_attn(const bf16* __restrict__ Q1, const bf16* __restrict__ K1,
               const bf16* __restrict__ Q2, const bf16* __restrict__ K2,
               const bf16* __restrict__ Vt, const float* __restrict__ lam_p,
               const float* __restrict__ subln_w, bf16* __restrict__ attn_out) {
    const int bid  = blockIdx.x;
    const int h    = bid & 31;
    const int pp   = bid >> 5;                    // 0..7
    const int tid  = threadIdx.x;
    const int wave = tid >> 6, lane = tid & 63;
    const int qhalf = wave >> 2, sid = (wave >> 1) & 1, ks = wave & 1;
    const int l = lane & 15, quad = lane >> 4;

    // 2 x 49152 B K/V double buffer; merge/epilogue reuse the first 36864 B.
    __shared__ __align__(16) char smem[98304];

    const bf16* K1g = K1 + (size_t)h * S_LEN * HD;
    const bf16* K2g = K2 + (size_t)h * S_LEN * HD;
    const bf16* Vtg = Vt + (size_t)h * HD * S_LEN;
    const bf16* Qv  = (sid ? Q2 : Q1) + (size_t)h * S_LEN * HD;

    const int rr  = tid >> 3;                     // 0..63 (512 threads)
    const int csw = ((tid & 7) ^ (rr & 7)) * 8;
    const int sw8 = l & 7;

    auto stage = [&](int kv, int bufb) {          // kv 128-aligned; 48 KB
        #pragma unroll
        for (int s = 0; s < 2; ++s) {
            gld16(K1g + (size_t)(kv + s * 64 + rr) * HD + csw,
                  (bf16*)(smem + bufb)         + s * 4096 + tid * 8);
            gld16(K2g + (size_t)(kv + s * 64 + rr) * HD + csw,
                  (bf16*)(smem + bufb + 16384) + s * 4096 + tid * 8);
            gld16(Vtg + (size_t)rr * S_LEN + kv + s * 64 + csw,
                  (bf16*)(smem + bufb + 32768) + s * 4096 + tid * 8);
        }
    };

    for (int it = 0; it < 2; ++it) {
        const int qb = it ? pp : (15 - pp);       // long item first
        const int q0 = qb * 128;
        const bf16* Qh = Qv + (size_t)(q0 + qhalf * 64) * HD;

        bf16x8 qf[4][2];
        #pragma unroll
        for (int g = 0; g < 4; ++g)
            #pragma unroll
            for (int dh = 0; dh < 2; ++dh)
                qf[g][dh] = *(const bf16x8*)(Qh + (g * 16 + l) * HD + dh * 32 + quad * 8);

        f32x4 O[4][4];                            // [g (q)][nd (d)] ks-partial
        #pragma unroll
        for (int g = 0; g < 4; ++g)
            #pragma unroll
            for (int nd = 0; nd < 4; ++nd)
                O[g][nd] = (f32x4){0.f, 0.f, 0.f, 0.f};
        float csum[4] = {0.f, 0.f, 0.f, 0.f};     // ks-partial row sums

        const int nt = qb + 1;                    // 128-row staged steps
        const int tq = 2 * qb + qhalf;            // this wave's diag sub-tile

        stage(0, 0);
        asm volatile("s_waitcnt vmcnt(0)" ::: "memory");
        __builtin_amdgcn_s_barrier();

        for (int tt = 0; tt < nt; ++tt) {
            const int bb = (tt & 1) * 49152;
            if (tt + 1 < nt) stage((tt + 1) * 128, 49152 - bb);

            #pragma unroll
            for (int sub = 0; sub < 2; ++sub) {
                const int t64 = 2 * tt + sub;
                if (t64 <= tq) {
                    const bf16* Ksm = (const bf16*)(smem + bb + (sid ? 16384 : 0))
                                      + sub * 4096;
                    const bf16* Vts = (const bf16*)(smem + bb + 32768) + sub * 4096;

                    bf16x8 ka[2][2];
                    #pragma unroll
                    for (int mk = 0; mk < 2; ++mk) {
                        const int krow = ((2 * ks + mk) * 16 + l) * 64;
                        ka[mk][0] = *(const bf16x8*)(Ksm + krow + ((quad ^ sw8) << 3));
                        ka[mk][1] = *(const bf16x8*)(Ksm + krow + (((4 + quad) ^ sw8) << 3));
                    }
                    bf16x8 vb[4];
                    #pragma unroll
                    for (int nd = 0; nd < 4; ++nd)
                        vb[nd] = *(const bf16x8*)(Vts + (nd * 16 + l) * 64 +
                                                  ((((ks << 2) + quad) ^ sw8) << 3));

                    __builtin_amdgcn_s_setprio(1);
                    if (t64 == tq) {
                        ATTN_CORE(1)
                    } else {
                        ATTN_CORE(0)
                    }
                    __builtin_amdgcn_s_setprio(0);
                }
            }

            asm volatile("s_waitcnt vmcnt(0)" ::: "memory");
            __builtin_amdgcn_s_barrier();
        }

        // ---------------- merge ks-halves (2 rounds by qhalf) ----------------
        __syncthreads();
        #pragma unroll
        for (int round = 0; round < 2; ++round) {
            float* dO = (float*)(smem + sid * 17408);        // [64][68] fp32
            float* dC = (float*)(smem + 34816 + sid * 1024);
            if (qhalf == round && ks == 1) {
                #pragma unroll
                for (int g = 0; g < 4; ++g)
                    #pragma unroll
                    for (int nd = 0; nd < 4; ++nd)
                        *(f32x4*)(dO + lane * 68 + (g * 4 + nd) * 4) = O[g][nd];
                #pragma unroll
                for (int g = 0; g < 4; ++g) dC[g * 64 + lane] = csum[g];
            }
            __syncthreads();
            if (qhalf == round && ks == 0) {
                #pragma unroll
                for (int g = 0; g < 4; ++g) {
                    #pragma unroll
                    for (int nd = 0; nd < 4; ++nd)
                        O[g][nd] += *(const f32x4*)(dO + lane * 68 + (g * 4 + nd) * 4);
                    csum[g] += dC[g * 64 + lane];
                }
            }
            __syncthreads();
        }

        // full row-sums: reduce across quads
        #pragma unroll
        for (int g = 0; g < 4; ++g) {
            csum[g] += __shfl_xor(csum[g], 16, 64);
            csum[g] += __shfl_xor(csum[g], 32, 64);
        }

        // ---------------- epilogue (ks==0 waves only) ----------------
        float* epi = (float*)smem;                // [128][65] fp32

        if (sid == 1 && ks == 0) {
            const float lam = lam_p[0];
            #pragma unroll
            for (int mi = 0; mi < 4; ++mi)
                #pragma unroll
                for (int r = 0; r < 4; ++r) {
                    const float inv = lam / __shfl(csum[mi], quad * 4 + r, 64);
                    const int row = qhalf * 64 + mi * 16 + quad * 4 + r;
                    #pragma unroll
                    for (int ni = 0; ni < 4; ++ni)
                        epi[row * 65 + ni * 16 + l] = O[mi][ni][r] * inv;
                }
        }
        __syncthreads();

        if (sid == 0 && ks == 0) {
            float sw[4];
            #pragma unroll
            for (int ni = 0; ni < 4; ++ni) sw[ni] = subln_w[ni * 16 + l];

            #pragma unroll
            for (int mi = 0; mi < 4; ++mi) {
                float inv1[4];
                #pragma unroll
                for (int r = 0; r < 4; ++r)
                    inv1[r] = 1.0f / __shfl(csum[mi], quad * 4 + r, 64);

                float v[4][4]; float ssq[4] = {0.f, 0.f, 0.f, 0.f};
                #pragma unroll
                for (int ni = 0; ni < 4; ++ni)
                    #pragma unroll
                    for (int r = 0; r < 4; ++r) {
                        const int row = qhalf * 64 + mi * 16 + quad * 4 + r;
                        const float x = O[mi][ni][r] * inv1[r] - epi[row * 65 + ni * 16 + l];
                        v[ni][r] = x;
                        ssq[r] += x * x;
                    }
                #pragma unroll
                for (int r = 0; r < 4; ++r) {
                    float s = ssq[r];
                    s += __shfl_xor(s, 1, 64);
                    s += __shfl_xor(s, 2, 64);
                    s += __shfl_xor(s, 4, 64);
                    s += __shfl_xor(s, 8, 64);
                    ssq[r] = rsqrtf(s * (1.0f / 64.0f) + RMS_EPS) * ONE_MINUS_LAM_INIT;
                }
                #pragma unroll
                for (int ni = 0; ni < 4; ++ni)
                    #pragma unroll
                    for (int r = 0; r < 4; ++r) {
                        const int row = q0 + qhalf * 64 + mi * 16 + quad * 4 + r;
                        attn_out[(size_t)row * HID_DIM + h * 64 + ni * 16 + l] =
                            (bf16)(v[ni][r] * ssq[r] * sw[ni]);
                    }
            }
        }
        __syncthreads();   // LDS safe for next item's staging
    }
}

// ---------------------------------------------------------------------------
// Workspace layout (bytes):
//   hsb   @ 0           8,388,608   hidden bf16
//   Wb    @ 8388608    41,943,040   Wq|Wk|Wv bf16
//   Wob   @ 50331648    8,388,608   Wo bf16
//   (58720256..100663295 unused — was split-K partials)
//   Q1    @ 100663296   8,388,608
//   K1    @ 109051904   8,388,608
//   Q2    @ 117440512   8,388,608
//   K2    @ 125829120   8,388,608
//   Vt    @ 134217728   8,388,608
//   abuf  @ 142606336   8,388,608
//   lam   @ 150994944   4
// ---------------------------------------------------------------------------
extern "C" void kernel_launch(void* const* d_in, const int* in_sizes, int n_in,
                              void* d_out, int out_size, void* d_ws, size_t ws_size,
                              hipStream_t stream) {
    const float* hs  = (const float*)d_in[0];
    const float* Wq  = (const float*)d_in[1];
    const float* Wk  = (const float*)d_in[2];
    const float* Wv  = (const float*)d_in[3];
    const float* Wo  = (const float*)d_in[4];
    const float* lq1 = (const float*)d_in[5];
    const float* lk1 = (const float*)d_in[6];
    const float* lq2 = (const float*)d_in[7];
    const float* lk2 = (const float*)d_in[8];
    const float* slw = (const float*)d_in[9];

    if (ws_size < 151000000u) return;

    char* ws = (char*)d_ws;
    bf16*  hsb  = (bf16*)(ws);
    bf16*  Wb   = (bf16*)(ws + 8388608);
    bf16*  Wob  = (bf16*)(ws + 50331648);
    bf16*  Q1b  = (bf16*)(ws + 100663296);
    bf16*  K1b  = (bf16*)(ws + 109051904);
    bf16*  Q2b  = (bf16*)(ws + 117440512);
    bf16*  K2b  = (bf16*)(ws + 125829120);
    bf16*  Vtb  = (bf16*)(ws + 134217728);
    bf16*  abuf = (bf16*)(ws + 142606336);
    float* lamp = (float*)(ws + 150994944);

    // 1) conversions + lambda
    cvt_all<<<14337, 256, 0, stream>>>(hs, Wq, Wk, Wv, Wo, lq1, lk1, lq2, lk2,
                                       hsb, Wb, Wob, lamp);

    // 2) fused QKV projection + RoPE + split + V transpose
    qkv_rope_gemm<<<dim3(QKV_N / 128, S_LEN / 128), 256, 0, stream>>>(
        hsb, Wb, Q1b, Q2b, K1b, K2b, Vtb);

    // 3) differential attention (256 blocks x 512 threads, KVBLK=128)
    diff_attn<<<256, 512, 0, stream>>>(Q1b, K1b, Q2b, K2b, Vtb, lamp, slw, abuf);

    // 4) output projection, full-K, direct fp32 store to d_out
    gemm_bt<<<dim3(16, 16), 256, 0, stream>>>(
        abuf, Wob, (float*)d_out, S_LEN, HID_DIM, HID_DIM);
}